// Round 10
// baseline (376.328 us; speedup 1.0000x reference)
//
#include <hip/hip_runtime.h>

// Problem constants (match reference)
constexpr int N_  = 10000;   // nodes
constexpr int E_  = 100000;  // edges per direction
constexpr int MP_ = 10112;   // N padded to multiple of 128 (79*128)

typedef unsigned int u32;
typedef unsigned short u16;
typedef __attribute__((ext_vector_type(8))) _Float16 f16x8;
typedef __attribute__((ext_vector_type(4))) _Float16 f16x4;
typedef __attribute__((ext_vector_type(2))) _Float16 f16x2;
typedef __attribute__((ext_vector_type(4))) float f32x4;

__device__ __forceinline__ u16 f2h(float f) {  // fp32 -> fp16 bits (RNE)
  _Float16 h = (_Float16)f;
  u16 r;
  __builtin_memcpy(&r, &h, 2);
  return r;
}
__device__ __forceinline__ void async16(const void* g, void* l) {
  // global -> LDS DMA, 16 B/lane; LDS dest = wave-uniform base + lane*16
  __builtin_amdgcn_global_load_lds((const __attribute__((address_space(1))) u32*)g,
                                   (__attribute__((address_space(3))) u32*)l, 16, 0, 0);
}

// ============================ fused prep: weights + x-cast + degree histogram ============================
// WCATh[l][j][k] (fp16, j in [0,2048) = [Wl_f|Wr_f|Wl_b|Wr_b] cols, TRANSPOSED k-contig)
// BCAT [l][2048] fp32; WM1h[l][n][k] k<256; WM2h[l][n][k] k<128 (transposed fp16)
// Xh = x cast to fp16 (padded); deg histograms for both directions.

__global__ void k_prep(const float* __restrict__ Wl_f, const float* __restrict__ Wr_f,
                       const float* __restrict__ Wl_b, const float* __restrict__ Wr_b,
                       const float* __restrict__ bl_f, const float* __restrict__ br_f,
                       const float* __restrict__ bl_b, const float* __restrict__ br_b,
                       const float* __restrict__ Wm1, const float* __restrict__ Wm2,
                       u16* __restrict__ WCATh, float* __restrict__ BCAT,
                       u16* __restrict__ WM1h, u16* __restrict__ WM2h,
                       const float* __restrict__ x, u16* __restrict__ Xh,
                       const int* __restrict__ fdst, const int* __restrict__ bdst,
                       int* __restrict__ degf, int* __restrict__ degb) {
  int idx = blockIdx.x * 256 + threadIdx.x;
  if (idx < 2 * 2048 * 128) {
    int l = idx >> 18;
    int rem = idx & 262143;
    int j = rem >> 7, k = rem & 127;
    int grp = j >> 9, jj = j & 511;
    const float* W = grp == 0 ? Wl_f : grp == 1 ? Wr_f : grp == 2 ? Wl_b : Wr_b;
    WCATh[idx] = f2h(W[((size_t)(l * 128 + k)) * 512 + jj]);
  }
  if (idx < 2 * 2048) {
    int l = idx >> 11, j = idx & 2047;
    int grp = j >> 9, jj = j & 511;
    const float* bs = grp == 0 ? bl_f : grp == 1 ? br_f : grp == 2 ? bl_b : br_b;
    BCAT[idx] = bs[l * 512 + jj];
  }
  if (idx < 2 * 128 * 256) {  // WM1h[(l*128+n)*256+k] = Wm1[(l*256+k)*128+n]
    int l = idx >> 15;
    int rem = idx & 32767;
    int n = rem >> 8, k = rem & 255;
    WM1h[idx] = f2h(Wm1[((size_t)(l * 256 + k)) * 128 + n]);
  }
  if (idx < 2 * 128 * 128) {  // WM2h[(l*128+n)*128+k] = Wm2[(l*128+k)*128+n]
    int l = idx >> 14;
    int rem = idx & 16383;
    int n = rem >> 7, k = rem & 127;
    WM2h[idx] = f2h(Wm2[((size_t)(l * 128 + k)) * 128 + n]);
  }
  if (idx < MP_ * 32) {  // x cast, one thread per 4 elems
    int row = idx >> 5;
    int c4 = (idx & 31) << 2;
    ushort4 o;
    if (row < N_) {
      float4 v = *reinterpret_cast<const float4*>(x + (size_t)row * 128 + c4);
      o.x = f2h(v.x); o.y = f2h(v.y); o.z = f2h(v.z); o.w = f2h(v.w);
    } else {
      o.x = o.y = o.z = o.w = 0;
    }
    *reinterpret_cast<ushort4*>(Xh + (size_t)row * 128 + c4) = o;
  }
  if (idx < E_) {
    atomicAdd(&degf[fdst[idx]], 1);
    atomicAdd(&degb[bdst[idx]], 1);
  }
}

__global__ void k_scan(const int* __restrict__ degf, const int* __restrict__ degb,
                       int* __restrict__ rpf, int* __restrict__ rpb) {
  const int* deg = blockIdx.x ? degb : degf;
  int* rp = blockIdx.x ? rpb : rpf;
  const int CH = 40;
  int t = threadIdx.x;
  int base = t * CH;
  int s = 0;
  for (int i = 0; i < CH; ++i) {
    int idx = base + i;
    if (idx < N_) s += deg[idx];
  }
  __shared__ int lds[256];
  lds[t] = s;
  __syncthreads();
  for (int off = 1; off < 256; off <<= 1) {
    int v = (t >= off) ? lds[t - off] : 0;
    __syncthreads();
    lds[t] += v;
    __syncthreads();
  }
  int run = lds[t] - s;
  for (int i = 0; i < CH; ++i) {
    int idx = base + i;
    if (idx < N_) { rp[idx] = run; run += deg[idx]; }
  }
  if (t == 255) rp[N_] = lds[255];
}

// degree-descending node permutation (counting sort, 1024 bins) — LPT scheduling
// for k_gat: high-degree (long) blocks dispatch first, shrinking the tail.
__global__ void k_dsort(const int* __restrict__ degf, const int* __restrict__ degb,
                        int* __restrict__ permf, int* __restrict__ permb) {
  const int dir = blockIdx.x;
  const int* deg = dir ? degb : degf;
  int* perm = dir ? permb : permf;
  __shared__ int cnt[1024];
  __shared__ int off[1024];
  int t = threadIdx.x;
  for (int i = t; i < 1024; i += 256) cnt[i] = 0;
  __syncthreads();
  for (int n = t; n < N_; n += 256) {
    int d = deg[n];
    if (d > 1023) d = 1023;
    atomicAdd(&cnt[d], 1);
  }
  __syncthreads();
  if (t == 0) {  // descending exclusive scan over bins
    int run = 0;
    for (int d = 1023; d >= 0; --d) { off[d] = run; run += cnt[d]; }
  }
  __syncthreads();
  for (int n = t; n < N_; n += 256) {
    int d = deg[n];
    if (d > 1023) d = 1023;
    int pos = atomicAdd(&off[d], 1);
    perm[pos] = n;
  }
}

// scatter both dirs (blockIdx.y): CSR src ids + eattr permuted to CSR order (fp16)
__global__ void k_scatter(const int* __restrict__ fwd, const int* __restrict__ bwd,
                          const int* __restrict__ rpf, const int* __restrict__ rpb,
                          int* __restrict__ curf, int* __restrict__ curb,
                          int* __restrict__ csf, int* __restrict__ csb,
                          u16* __restrict__ ePf, u16* __restrict__ ePb,
                          const float* __restrict__ eattr) {
  int e = blockIdx.x * 256 + threadIdx.x;
  if (e >= E_) return;
  const int dirb = blockIdx.y;
  const int* src = dirb ? bwd : fwd;
  const int* dst = (dirb ? bwd : fwd) + E_;
  const int* rp = dirb ? rpb : rpf;
  int* cur = dirb ? curb : curf;
  int* csrc = dirb ? csb : csf;
  u16* ePh = dirb ? ePb : ePf;
  int d = dst[e];
  int pos = rp[d] + atomicAdd(&cur[d], 1);
  csrc[pos] = src[e];
  const float4* s4 = reinterpret_cast<const float4*>(eattr + (size_t)e * 16);
  float4 a = s4[0], b = s4[1], c = s4[2], dd = s4[3];
  ushort4 o0, o1, o2, o3;
  o0.x = f2h(a.x); o0.y = f2h(a.y); o0.z = f2h(a.z); o0.w = f2h(a.w);
  o1.x = f2h(b.x); o1.y = f2h(b.y); o1.z = f2h(b.z); o1.w = f2h(b.w);
  o2.x = f2h(c.x); o2.y = f2h(c.y); o2.z = f2h(c.z); o2.w = f2h(c.w);
  o3.x = f2h(dd.x); o3.y = f2h(dd.y); o3.z = f2h(dd.z); o3.w = f2h(dd.w);
  ushort4* d4 = reinterpret_cast<ushort4*>(ePh + (size_t)pos * 16);
  d4[0] = o0; d4[1] = o1; d4[2] = o2; d4[3] = o3;
}

// ============================ fp16 MFMA GEMM (big) ============================
// C[M, Ncols] = A[Mpad, K](fp16) @ Bt[Ncols, K]^T(fp16) + bias(fp32) -> fp16
// 128x128 tile, 4 waves (64x64 quadrant each), global_load_lds staging.
// OPERAND-SWAPPED MFMA: mfma(weights, nodes, acc) so D's lane index = node row and
// the reg-run = 4 consecutive output cols -> ushort4 (8B) epilogue stores.

template <int K>
__global__ __launch_bounds__(256) void k_hgemm(const u16* __restrict__ A,
                                               const u16* __restrict__ Bt,
                                               const float* __restrict__ bias,
                                               u16* __restrict__ Cb, int M, int Ncols) {
  __shared__ __align__(16) u16 As[128 * 128];
  __shared__ __align__(16) u16 Bs[128 * 128];
  const int tid = threadIdx.x;
  const int lane = tid & 63, wave = tid >> 6;
  const int l16 = lane & 15, lq = lane >> 4;
  const int wm = wave & 1, wn = wave >> 1;
  const u16* Arow0 = A + (size_t)blockIdx.y * 128 * K;
  const u16* Brow0 = Bt + (size_t)blockIdx.x * 128 * K;

  f32x4 acc[4][4];  // acc[i=col tile][j=node tile]
#pragma unroll
  for (int i = 0; i < 4; ++i)
#pragma unroll
    for (int j = 0; j < 4; ++j) acc[i][j] = (f32x4){0.f, 0.f, 0.f, 0.f};

  for (int kc = 0; kc < K; kc += 128) {
    if (kc) __syncthreads();
#pragma unroll
    for (int i = 0; i < 8; ++i) {
      int rg = i * 4 + wave;
      int r = rg * 4 + (lane >> 4);
      int cc = kc + (lane & 15) * 8;
      async16(Arow0 + (size_t)r * K + cc, (char*)As + rg * 1024);
      async16(Brow0 + (size_t)r * K + cc, (char*)Bs + rg * 1024);
    }
    __syncthreads();
    const u16* Ab = As + (wm * 64 + l16) * 128 + lq * 8;  // nodes
    const u16* Bb = Bs + (wn * 64 + l16) * 128 + lq * 8;  // weight cols
#pragma unroll
    for (int ks = 0; ks < 4; ++ks) {
      f16x8 af[4], bfr[4];
#pragma unroll
      for (int j = 0; j < 4; ++j)
        af[j] = *reinterpret_cast<const f16x8*>(Ab + j * 16 * 128 + ks * 32);
#pragma unroll
      for (int i = 0; i < 4; ++i)
        bfr[i] = *reinterpret_cast<const f16x8*>(Bb + i * 16 * 128 + ks * 32);
#pragma unroll
      for (int i = 0; i < 4; ++i)
#pragma unroll
        for (int j = 0; j < 4; ++j)
          acc[i][j] = __builtin_amdgcn_mfma_f32_16x16x32_f16(bfr[i], af[j], acc[i][j], 0, 0, 0);
    }
  }

  // Epilogue: lane&15 = node (within j-tile), lq*4+reg = col (within i-tile)
  const int node_base = blockIdx.y * 128 + wm * 64;
  const int col_base = blockIdx.x * 128 + wn * 64;
#pragma unroll
  for (int i = 0; i < 4; ++i) {
    int col0 = col_base + i * 16 + lq * 4;
    float4 bb = *reinterpret_cast<const float4*>(bias + col0);
#pragma unroll
    for (int j = 0; j < 4; ++j) {
      int node = node_base + j * 16 + l16;
      if (node < M) {
        ushort4 o;
        o.x = f2h(acc[i][j][0] + bb.x);
        o.y = f2h(acc[i][j][1] + bb.y);
        o.z = f2h(acc[i][j][2] + bb.z);
        o.w = f2h(acc[i][j][3] + bb.w);
        *reinterpret_cast<ushort4*>(Cb + (size_t)node * Ncols + col0) = o;
      }
    }
  }
}

// ============================ GATv2 aggregation (fused, 4-edge unroll, LPT order) ============================
// Block = one (node, dir) with node = perm[dir][blockIdx.x] (degree-descending -> long
// blocks dispatch first, shrinking the end-of-kernel tail). 128 threads, 4 ch each;
// heads = 32-lane groups. 4 independent gather+eattr chains in flight (latency-bound).
// EE chain in pk-f16; softmax sums fp32 (unnormalized, divide at end).

__global__ __launch_bounds__(128, 4) void k_gat(
    const u16* __restrict__ XLXRh,
    const int* __restrict__ rpf, const int* __restrict__ csf, const u16* __restrict__ ePf,
    const int* __restrict__ rpb, const int* __restrict__ csb, const u16* __restrict__ ePb,
    const int* __restrict__ permf, const int* __restrict__ permb,
    const float* __restrict__ We_f, const float* __restrict__ We_b,
    const float* __restrict__ att_f, const float* __restrict__ att_b,
    const float* __restrict__ bias_f, const float* __restrict__ bias_b,
    u16* __restrict__ FBh, int layer) {
  const int dir = blockIdx.y;
  const int n = (dir ? permb : permf)[blockIdx.x];
  const int* rp = dir ? rpb : rpf;
  const int* cs = dir ? csb : csf;
  const u16* eP = dir ? ePb : ePf;
  const float* We = (dir ? We_b : We_f) + layer * 16 * 512;
  const float* att = (dir ? att_b : att_f) + layer * 512;
  const float* bias = (dir ? bias_b : bias_f) + layer * 128;
  const int t = threadIdx.x;
  const int ch = t << 2;
  const u16* XL = XLXRh + dir * 1024;  // cols [dir*1024, +512) of (N,2048)
  const u16* XR = XL + 512;

  f32x4 a4 = *reinterpret_cast<const f32x4*>(att + ch);
  f16x4 xrh = *reinterpret_cast<const f16x4*>(XR + (size_t)n * 2048 + ch);
  f16x2 xr01 = {xrh.x, xrh.y}, xr23 = {xrh.z, xrh.w};
  f16x2 we01[16], we23[16];  // packed fp16 We rows for this lane's 4 ch
#pragma unroll
  for (int k = 0; k < 16; ++k) {
    float4 w = *reinterpret_cast<const float4*>(We + k * 512 + ch);
    we01[k] = (f16x2){(_Float16)w.x, (_Float16)w.y};
    we23[k] = (f16x2){(_Float16)w.z, (_Float16)w.w};
  }

  // per-lane pre-reduction partial: z = xl+xr+E@We (fp16 pk) -> leaky -> att-dot (f32)
  auto pre = [&](f16x4 x, f16x8 eL, f16x8 eH) -> float {
    f16x2 z01 = (f16x2){x.x, x.y} + xr01;
    f16x2 z23 = (f16x2){x.z, x.w} + xr23;
#pragma unroll
    for (int k = 0; k < 16; ++k) {
      _Float16 sc = (k < 8) ? eL[k] : eH[k - 8];
      f16x2 c = {sc, sc};
      z01 = __builtin_elementwise_fma(c, we01[k], z01);
      z23 = __builtin_elementwise_fma(c, we23[k], z23);
    }
    const f16x2 hz = {(_Float16)0.f, (_Float16)0.f};
    const f16x2 hs = {(_Float16)0.2f, (_Float16)0.2f};
    f16x2 l01 = __builtin_elementwise_fma(hs, __builtin_elementwise_min(z01, hz),
                                          __builtin_elementwise_max(z01, hz));
    f16x2 l23 = __builtin_elementwise_fma(hs, __builtin_elementwise_min(z23, hz),
                                          __builtin_elementwise_max(z23, hz));
    return fmaf((float)l01.x, a4.x,
           fmaf((float)l01.y, a4.y,
           fmaf((float)l23.x, a4.z, (float)l23.y * a4.w)));
  };
  auto accum = [&](float ex, f16x4 x, f32x4& acc) {
    f32x4 xf = {(float)x.x, (float)x.y, (float)x.z, (float)x.w};
    acc = __builtin_elementwise_fma((f32x4){ex, ex, ex, ex}, xf, acc);
  };

  f32x4 acc = {0.f, 0.f, 0.f, 0.f};
  float denom = 0.f;
  const int s = rp[n], epos = rp[n + 1];
  int i = s;
  for (; i + 4 <= epos; i += 4) {
    // 4 independent gather chains in flight
    int s0 = cs[i], s1 = cs[i + 1], s2 = cs[i + 2], s3 = cs[i + 3];
    f16x4 x0 = *reinterpret_cast<const f16x4*>(XL + (size_t)s0 * 2048 + ch);
    f16x4 x1 = *reinterpret_cast<const f16x4*>(XL + (size_t)s1 * 2048 + ch);
    f16x4 x2 = *reinterpret_cast<const f16x4*>(XL + (size_t)s2 * 2048 + ch);
    f16x4 x3 = *reinterpret_cast<const f16x4*>(XL + (size_t)s3 * 2048 + ch);
    f16x8 e0L = *reinterpret_cast<const f16x8*>(eP + (size_t)i * 16);
    f16x8 e0H = *reinterpret_cast<const f16x8*>(eP + (size_t)i * 16 + 8);
    f16x8 e1L = *reinterpret_cast<const f16x8*>(eP + (size_t)(i + 1) * 16);
    f16x8 e1H = *reinterpret_cast<const f16x8*>(eP + (size_t)(i + 1) * 16 + 8);
    f16x8 e2L = *reinterpret_cast<const f16x8*>(eP + (size_t)(i + 2) * 16);
    f16x8 e2H = *reinterpret_cast<const f16x8*>(eP + (size_t)(i + 2) * 16 + 8);
    f16x8 e3L = *reinterpret_cast<const f16x8*>(eP + (size_t)(i + 3) * 16);
    f16x8 e3H = *reinterpret_cast<const f16x8*>(eP + (size_t)(i + 3) * 16 + 8);
    float pA = pre(x0, e0L, e0H);
    float pB = pre(x1, e1L, e1H);
    float pC = pre(x2, e2L, e2H);
    float pD = pre(x3, e3L, e3H);
    // interleaved per-head (32-lane group) reductions
#pragma unroll
    for (int kk = 1; kk < 32; kk <<= 1) {
      pA += __shfl_xor(pA, kk, 32);
      pB += __shfl_xor(pB, kk, 32);
      pC += __shfl_xor(pC, kk, 32);
      pD += __shfl_xor(pD, kk, 32);
    }
    float ex0 = __expf(pA);  // logits O(+-3): no max-subtraction needed
    float ex1 = __expf(pB);
    float ex2 = __expf(pC);
    float ex3 = __expf(pD);
    denom += (ex0 + ex1) + (ex2 + ex3);
    accum(ex0, x0, acc);
    accum(ex1, x1, acc);
    accum(ex2, x2, acc);
    accum(ex3, x3, acc);
  }
  for (; i < epos; ++i) {
    int s0 = cs[i];
    f16x4 x0 = *reinterpret_cast<const f16x4*>(XL + (size_t)s0 * 2048 + ch);
    f16x8 e0L = *reinterpret_cast<const f16x8*>(eP + (size_t)i * 16);
    f16x8 e0H = *reinterpret_cast<const f16x8*>(eP + (size_t)i * 16 + 8);
    float pA = pre(x0, e0L, e0H);
#pragma unroll
    for (int kk = 1; kk < 32; kk <<= 1) pA += __shfl_xor(pA, kk, 32);
    float ex0 = __expf(pA);
    denom += ex0;
    accum(ex0, x0, acc);
  }

  __shared__ __align__(16) float red[512];
  float inv = denom > 0.f ? 1.f / denom : 0.f;  // deg==0 -> out = bias
  *reinterpret_cast<f32x4*>(&red[ch]) = acc * inv;
  __syncthreads();
  if (t < 32) {  // head mean + bias -> fp16
    int c = t << 2;
    f32x4 r0 = *reinterpret_cast<const f32x4*>(&red[c]);
    f32x4 r1 = *reinterpret_cast<const f32x4*>(&red[c + 128]);
    f32x4 r2 = *reinterpret_cast<const f32x4*>(&red[c + 256]);
    f32x4 r3 = *reinterpret_cast<const f32x4*>(&red[c + 384]);
    f32x4 b4 = *reinterpret_cast<const f32x4*>(bias + c);
    f32x4 o = (r0 + r1 + r2 + r3) * 0.25f + b4;
    ushort4 oh;
    oh.x = f2h(o.x); oh.y = f2h(o.y); oh.z = f2h(o.z); oh.w = f2h(o.w);
    *reinterpret_cast<ushort4*>(FBh + (size_t)n * 256 + dir * 128 + c) = oh;
  }
}

// ============================ fused merge MLP + BN stats ============================

__global__ __launch_bounds__(256) void k_mlp(const u16* __restrict__ FBh,
                                             const u16* __restrict__ W1,
                                             const float* __restrict__ b1,
                                             const u16* __restrict__ W2,
                                             const float* __restrict__ b2,
                                             float* __restrict__ M2,
                                             float* __restrict__ STATS) {
  __shared__ __align__(16) u16 As[128 * 128];   // W1 chunk [n][k=128], then W2 [n2][k2]
  __shared__ __align__(16) u16 Bs[64 * 128];    // FB chunk [m][k=128]
  __shared__ __align__(16) u16 M1s[64 * 128];   // M1 [m][k2=128] fp16
  __shared__ float ls[256];
  const int tid = threadIdx.x;
  const int lane = tid & 63, wave = tid >> 6;
  const int l16 = lane & 15, lq = lane >> 4;
  const int mb = blockIdx.x * 64;

  // ---- GEMM1: M1T[128 feat][64 nodes], K=256 ----
  const int wr = wave & 1, wc = wave >> 1;
  f32x4 acc1[4][2];
#pragma unroll
  for (int i = 0; i < 4; ++i)
#pragma unroll
    for (int j = 0; j < 2; ++j) acc1[i][j] = (f32x4){0.f, 0.f, 0.f, 0.f};

  for (int kc = 0; kc < 256; kc += 128) {
    if (kc) __syncthreads();
#pragma unroll
    for (int tI = 0; tI < 8; ++tI) {  // W1: 128 rows x 256B
      int rg = tI * 4 + wave;
      int r = rg * 4 + (lane >> 4);
      async16(W1 + (size_t)r * 256 + kc + (lane & 15) * 8, (char*)As + rg * 1024);
    }
#pragma unroll
    for (int tI = 0; tI < 4; ++tI) {  // FB: 64 rows x 256B
      int rg = tI * 4 + wave;
      int r = rg * 4 + (lane >> 4);
      async16(FBh + (size_t)(mb + r) * 256 + kc + (lane & 15) * 8, (char*)Bs + rg * 1024);
    }
    __syncthreads();
#pragma unroll
    for (int ks = 0; ks < 4; ++ks) {
      f16x8 af[4], bfv[2];
#pragma unroll
      for (int i = 0; i < 4; ++i)
        af[i] = *reinterpret_cast<const f16x8*>(As + (wr * 64 + i * 16 + l16) * 128 + ks * 32 + lq * 8);
#pragma unroll
      for (int j = 0; j < 2; ++j)
        bfv[j] = *reinterpret_cast<const f16x8*>(Bs + (wc * 32 + j * 16 + l16) * 128 + ks * 32 + lq * 8);
#pragma unroll
      for (int i = 0; i < 4; ++i)
#pragma unroll
        for (int j = 0; j < 2; ++j)
          acc1[i][j] = __builtin_amdgcn_mfma_f32_16x16x32_f16(af[i], bfv[j], acc1[i][j], 0, 0, 0);
    }
  }
  ls[tid] = 0.f;  // zero stats partials (used after 2 barriers)
  // epilogue1: bias + relu -> fp16 -> M1s[m][k2] (r-run contiguous in k2)
#pragma unroll
  for (int i = 0; i < 4; ++i) {
    float4 b1v = *reinterpret_cast<const float4*>(b1 + wr * 64 + i * 16 + lq * 4);
    float bb[4] = {b1v.x, b1v.y, b1v.z, b1v.w};
#pragma unroll
    for (int j = 0; j < 2; ++j) {
      int m = wc * 32 + j * 16 + l16;
      int k2 = wr * 64 + i * 16 + lq * 4;
      ushort4 o;
      o.x = f2h(fmaxf(acc1[i][j][0] + bb[0], 0.f));
      o.y = f2h(fmaxf(acc1[i][j][1] + bb[1], 0.f));
      o.z = f2h(fmaxf(acc1[i][j][2] + bb[2], 0.f));
      o.w = f2h(fmaxf(acc1[i][j][3] + bb[3], 0.f));
      *reinterpret_cast<ushort4*>(M1s + m * 128 + k2) = o;
    }
  }
  __syncthreads();  // M1s visible; As free for W2
#pragma unroll
  for (int tI = 0; tI < 8; ++tI) {  // W2: 128 rows x 256B
    int rg = tI * 4 + wave;
    int r = rg * 4 + (lane >> 4);
    async16(W2 + (size_t)r * 128 + (lane & 15) * 8, (char*)As + rg * 1024);
  }
  __syncthreads();

  // ---- GEMM2: M2[64 nodes][128 feat], K=128 ----
  const int wr2 = wave & 1, wc2 = wave >> 1;
  f32x4 acc2[2][4];
#pragma unroll
  for (int i = 0; i < 2; ++i)
#pragma unroll
    for (int j = 0; j < 4; ++j) acc2[i][j] = (f32x4){0.f, 0.f, 0.f, 0.f};
#pragma unroll
  for (int ks = 0; ks < 4; ++ks) {
    f16x8 af2[2], bf2v[4];
#pragma unroll
    for (int i = 0; i < 2; ++i)
      af2[i] = *reinterpret_cast<const f16x8*>(M1s + (wr2 * 32 + i * 16 + l16) * 128 + ks * 32 + lq * 8);
#pragma unroll
    for (int j = 0; j < 4; ++j)
      bf2v[j] = *reinterpret_cast<const f16x8*>(As + (wc2 * 64 + j * 16 + l16) * 128 + ks * 32 + lq * 8);
#pragma unroll
    for (int i = 0; i < 2; ++i)
#pragma unroll
      for (int j = 0; j < 4; ++j)
        acc2[i][j] = __builtin_amdgcn_mfma_f32_16x16x32_f16(af2[i], bf2v[j], acc2[i][j], 0, 0, 0);
  }

  // epilogue2: bias, store M2 (valid rows), BN stats partials
  float s1[4] = {0.f, 0.f, 0.f, 0.f}, s2[4] = {0.f, 0.f, 0.f, 0.f};
  float b2j[4];
#pragma unroll
  for (int j = 0; j < 4; ++j) b2j[j] = b2[wc2 * 64 + j * 16 + l16];
#pragma unroll
  for (int i = 0; i < 2; ++i) {
#pragma unroll
    for (int r = 0; r < 4; ++r) {
      int m = mb + wr2 * 32 + i * 16 + lq * 4 + r;
      if (m < N_) {
#pragma unroll
        for (int j = 0; j < 4; ++j) {
          float v = acc2[i][j][r] + b2j[j];
          M2[(size_t)m * 128 + wc2 * 64 + j * 16 + l16] = v;
          s1[j] += v;
          s2[j] = fmaf(v, v, s2[j]);
        }
      }
    }
  }
#pragma unroll
  for (int j = 0; j < 4; ++j) {
    int c = wc2 * 64 + j * 16 + l16;
    atomicAdd(&ls[c], s1[j]);
    atomicAdd(&ls[128 + c], s2[j]);
  }
  __syncthreads();
  if (tid < 128) {
    atomicAdd(&STATS[tid], ls[tid]);
    atomicAdd(&STATS[128 + tid], ls[128 + tid]);
  }
}

// ============================ BatchNorm finalize ============================

__global__ void k_bn(const float* __restrict__ m2, const float* __restrict__ stats,
                     const float* __restrict__ gamma, const float* __restrict__ beta,
                     u16* __restrict__ houth, float* __restrict__ outf) {
  int idx = blockIdx.x * 256 + threadIdx.x;
  if (idx >= N_ * 32) return;
  int n = idx >> 5;
  int c = (idx & 31) << 2;
  float4 v = *reinterpret_cast<const float4*>(m2 + (size_t)n * 128 + c);
  const float invN = 1.f / (float)N_;
  float o[4];
  float vv[4] = {v.x, v.y, v.z, v.w};
#pragma unroll
  for (int q = 0; q < 4; ++q) {
    float mu = stats[c + q] * invN;
    float var = stats[128 + c + q] * invN - mu * mu;
    float rs = rsqrtf(var + 1e-5f);
    o[q] = fmaxf(gamma[c + q] * (vv[q] - mu) * rs + beta[c + q], 0.f);
  }
  ushort4 oh;
  oh.x = f2h(o[0]); oh.y = f2h(o[1]); oh.z = f2h(o[2]); oh.w = f2h(o[3]);
  *reinterpret_cast<ushort4*>(houth + (size_t)n * 128 + c) = oh;
  if (outf) {
    float4 of = make_float4(o[0], o[1], o[2], o[3]);
    *reinterpret_cast<float4*>(outf + (size_t)n * 128 + c) = of;
  }
}

// ============================ launch ============================

extern "C" void kernel_launch(void* const* d_in, const int* in_sizes, int n_in,
                              void* d_out, int out_size, void* d_ws, size_t ws_size,
                              hipStream_t stream) {
  (void)in_sizes; (void)n_in; (void)out_size; (void)ws_size;
  const float* x      = (const float*)d_in[0];
  const int*   fwd    = (const int*)d_in[1];
  const int*   bwd    = (const int*)d_in[2];
  const float* eattr  = (const float*)d_in[3];
  const float* Wl_f   = (const float*)d_in[4];
  const float* bl_f   = (const float*)d_in[5];
  const float* Wr_f   = (const float*)d_in[6];
  const float* br_f   = (const float*)d_in[7];
  const float* We_f   = (const float*)d_in[8];
  const float* att_f  = (const float*)d_in[9];
  const float* bias_f = (const float*)d_in[10];
  const float* Wl_b   = (const float*)d_in[11];
  const float* bl_b   = (const float*)d_in[12];
  const float* Wr_b   = (const float*)d_in[13];
  const float* br_b   = (const float*)d_in[14];
  const float* We_b   = (const float*)d_in[15];
  const float* att_b  = (const float*)d_in[16];
  const float* bias_b = (const float*)d_in[17];
  const float* Wm1    = (const float*)d_in[18];
  const float* bm1    = (const float*)d_in[19];
  const float* Wm2    = (const float*)d_in[20];
  const float* bm2    = (const float*)d_in[21];
  const float* gamma  = (const float*)d_in[22];
  const float* beta   = (const float*)d_in[23];

  char* ws = (char*)d_ws;
  size_t off = 0;
  auto take = [&](size_t bytes) -> char* {
    char* p = ws + off;
    off += (bytes + 255) & ~(size_t)255;
    return p;
  };
  u16* WCATh = (u16*)take(2ull * 2048 * 128 * 2);
  float* BCAT = (float*)take(2ull * 2048 * 4);
  u16* WM1h = (u16*)take(2ull * 128 * 256 * 2);
  u16* WM2h = (u16*)take(2ull * 128 * 128 * 2);
  u16* Xh    = (u16*)take((size_t)MP_ * 128 * 2);
  u16* HBh   = (u16*)take((size_t)MP_ * 128 * 2);
  u16* XLXRh = (u16*)take((size_t)MP_ * 2048 * 2);
  u16* FBh   = (u16*)take((size_t)MP_ * 256 * 2);
  float* M2  = (float*)take((size_t)MP_ * 128 * 4);
  // DEGS + STATS contiguous: one memset zeroes both
  int* DEGS  = (int*)take(4ull * 40192);
  float* STATS = (float*)take(2ull * 256 * 4);  // per-layer slots
  int* degf = DEGS;
  int* degb = DEGS + (40192 / 4);
  int* curf = DEGS + 2 * (40192 / 4);
  int* curb = DEGS + 3 * (40192 / 4);
  int* rpf = (int*)take((N_ + 1) * 4);
  int* rpb = (int*)take((N_ + 1) * 4);
  int* csf = (int*)take((size_t)E_ * 4);
  int* csb = (int*)take((size_t)E_ * 4);
  int* permf = (int*)take((size_t)N_ * 4);
  int* permb = (int*)take((size_t)N_ * 4);
  u16* ePf = (u16*)take((size_t)E_ * 16 * 2 + 256);
  u16* ePb = (u16*)take((size_t)E_ * 16 * 2 + 256);

  // prep: fused (weights fp16/transposed, x cast, degree hist), scan, dsort, scatter
  hipMemsetAsync(DEGS, 0, 4ull * 40192 + 2ull * 256 * 4, stream);
  k_prep<<<2048, 256, 0, stream>>>(Wl_f, Wr_f, Wl_b, Wr_b, bl_f, br_f, bl_b, br_b,
                                   Wm1, Wm2, WCATh, BCAT, WM1h, WM2h,
                                   x, Xh, fwd + E_, bwd + E_, degf, degb);
  k_scan<<<2, 256, 0, stream>>>(degf, degb, rpf, rpb);
  k_dsort<<<2, 256, 0, stream>>>(degf, degb, permf, permb);
  k_scatter<<<dim3((E_ + 255) / 256, 2), 256, 0, stream>>>(
      fwd, bwd, rpf, rpb, curf, curb, csf, csb, ePf, ePb, eattr);

  for (int l = 0; l < 2; ++l) {
    const u16* hin = (l == 0) ? Xh : HBh;
    // XLXR = hin @ [Wl_f|Wr_f|Wl_b|Wr_b] + biases -> fp16 (N,2048)
    k_hgemm<128><<<dim3(16, MP_ / 128), 256, 0, stream>>>(
        hin, WCATh + (size_t)l * 2048 * 128, BCAT + l * 2048, XLXRh, N_, 2048);
    // GAT aggregation (fused, LPT-ordered), both directions -> FBh (N,256) = [f | b]
    k_gat<<<dim3(N_, 2), 128, 0, stream>>>(XLXRh, rpf, csf, ePf, rpb, csb, ePb,
                                           permf, permb, We_f, We_b, att_f, att_b,
                                           bias_f, bias_b, FBh, l);
    // fused merge MLP + BN stats
    k_mlp<<<MP_ / 64, 256, 0, stream>>>(FBh, WM1h + (size_t)l * 128 * 256, bm1 + l * 128,
                                        WM2h + (size_t)l * 128 * 128, bm2 + l * 128, M2,
                                        STATS + l * 256);
    // BN finalize + ReLU
    k_bn<<<(N_ * 32 + 255) / 256, 256, 0, stream>>>(
        M2, STATS + l * 256, gamma + l * 128, beta + l * 128, HBh,
        (l == 1) ? (float*)d_out : nullptr);
  }
}

// Round 11
// 366.953 us; speedup vs baseline: 1.0255x; 1.0255x over previous
//
#include <hip/hip_runtime.h>

// Problem constants (match reference)
constexpr int N_  = 10000;   // nodes
constexpr int E_  = 100000;  // edges per direction
constexpr int MP_ = 10112;   // N padded to multiple of 128 (79*128)

typedef unsigned int u32;
typedef unsigned short u16;
typedef __attribute__((ext_vector_type(8))) _Float16 f16x8;
typedef __attribute__((ext_vector_type(4))) _Float16 f16x4;
typedef __attribute__((ext_vector_type(2))) _Float16 f16x2;
typedef __attribute__((ext_vector_type(4))) float f32x4;

__device__ __forceinline__ u16 f2h(float f) {  // fp32 -> fp16 bits (RNE)
  _Float16 h = (_Float16)f;
  u16 r;
  __builtin_memcpy(&r, &h, 2);
  return r;
}
__device__ __forceinline__ void async16(const void* g, void* l) {
  // global -> LDS DMA, 16 B/lane; LDS dest = wave-uniform base + lane*16
  __builtin_amdgcn_global_load_lds((const __attribute__((address_space(1))) u32*)g,
                                   (__attribute__((address_space(3))) u32*)l, 16, 0, 0);
}

// ============================ fused prep: weights + x-cast + degree histogram ============================
// WCATh[l][j][k] (fp16, j in [0,2048) = [Wl_f|Wr_f|Wl_b|Wr_b] cols, TRANSPOSED k-contig)
// BCAT [l][2048] fp32; WM1h[l][n][k] k<256; WM2h[l][n][k] k<128 (transposed fp16)
// Xh = x cast to fp16 (padded); deg histograms for both directions.

__global__ void k_prep(const float* __restrict__ Wl_f, const float* __restrict__ Wr_f,
                       const float* __restrict__ Wl_b, const float* __restrict__ Wr_b,
                       const float* __restrict__ bl_f, const float* __restrict__ br_f,
                       const float* __restrict__ bl_b, const float* __restrict__ br_b,
                       const float* __restrict__ Wm1, const float* __restrict__ Wm2,
                       u16* __restrict__ WCATh, float* __restrict__ BCAT,
                       u16* __restrict__ WM1h, u16* __restrict__ WM2h,
                       const float* __restrict__ x, u16* __restrict__ Xh,
                       const int* __restrict__ fdst, const int* __restrict__ bdst,
                       int* __restrict__ degf, int* __restrict__ degb) {
  int idx = blockIdx.x * 256 + threadIdx.x;
  if (idx < 2 * 2048 * 128) {
    int l = idx >> 18;
    int rem = idx & 262143;
    int j = rem >> 7, k = rem & 127;
    int grp = j >> 9, jj = j & 511;
    const float* W = grp == 0 ? Wl_f : grp == 1 ? Wr_f : grp == 2 ? Wl_b : Wr_b;
    WCATh[idx] = f2h(W[((size_t)(l * 128 + k)) * 512 + jj]);
  }
  if (idx < 2 * 2048) {
    int l = idx >> 11, j = idx & 2047;
    int grp = j >> 9, jj = j & 511;
    const float* bs = grp == 0 ? bl_f : grp == 1 ? br_f : grp == 2 ? bl_b : br_b;
    BCAT[idx] = bs[l * 512 + jj];
  }
  if (idx < 2 * 128 * 256) {  // WM1h[(l*128+n)*256+k] = Wm1[(l*256+k)*128+n]
    int l = idx >> 15;
    int rem = idx & 32767;
    int n = rem >> 8, k = rem & 255;
    WM1h[idx] = f2h(Wm1[((size_t)(l * 256 + k)) * 128 + n]);
  }
  if (idx < 2 * 128 * 128) {  // WM2h[(l*128+n)*128+k] = Wm2[(l*128+k)*128+n]
    int l = idx >> 14;
    int rem = idx & 16383;
    int n = rem >> 7, k = rem & 127;
    WM2h[idx] = f2h(Wm2[((size_t)(l * 128 + k)) * 128 + n]);
  }
  if (idx < MP_ * 32) {  // x cast, one thread per 4 elems
    int row = idx >> 5;
    int c4 = (idx & 31) << 2;
    ushort4 o;
    if (row < N_) {
      float4 v = *reinterpret_cast<const float4*>(x + (size_t)row * 128 + c4);
      o.x = f2h(v.x); o.y = f2h(v.y); o.z = f2h(v.z); o.w = f2h(v.w);
    } else {
      o.x = o.y = o.z = o.w = 0;
    }
    *reinterpret_cast<ushort4*>(Xh + (size_t)row * 128 + c4) = o;
  }
  if (idx < E_) {
    atomicAdd(&degf[fdst[idx]], 1);
    atomicAdd(&degb[bdst[idx]], 1);
  }
}

__global__ void k_scan(const int* __restrict__ degf, const int* __restrict__ degb,
                       int* __restrict__ rpf, int* __restrict__ rpb) {
  const int* deg = blockIdx.x ? degb : degf;
  int* rp = blockIdx.x ? rpb : rpf;
  const int CH = 40;
  int t = threadIdx.x;
  int base = t * CH;
  int s = 0;
  for (int i = 0; i < CH; ++i) {
    int idx = base + i;
    if (idx < N_) s += deg[idx];
  }
  __shared__ int lds[256];
  lds[t] = s;
  __syncthreads();
  for (int off = 1; off < 256; off <<= 1) {
    int v = (t >= off) ? lds[t - off] : 0;
    __syncthreads();
    lds[t] += v;
    __syncthreads();
  }
  int run = lds[t] - s;
  for (int i = 0; i < CH; ++i) {
    int idx = base + i;
    if (idx < N_) { rp[idx] = run; run += deg[idx]; }
  }
  if (t == 255) rp[N_] = lds[255];
}

// degree-descending node permutation (counting sort, 1024 bins, PARALLEL scan) —
// LPT scheduling for k_gat: long blocks dispatch first, shrinking the tail.
// (r10 post-mortem: the t==0 serial 1024-bin scan cost ~12us; now LDS-scanned.)
__global__ void k_dsort(const int* __restrict__ degf, const int* __restrict__ degb,
                        int* __restrict__ permf, int* __restrict__ permb) {
  const int dir = blockIdx.x;
  const int* deg = dir ? degb : degf;
  int* perm = dir ? permb : permf;
  __shared__ int cnt[1024];
  __shared__ int off[1024];
  __shared__ int lds[256];
  int t = threadIdx.x;
  for (int i = t; i < 1024; i += 256) cnt[i] = 0;
  __syncthreads();
  for (int n = t; n < N_; n += 256) {
    int d = deg[n];
    if (d > 1023) d = 1023;
    atomicAdd(&cnt[d], 1);
  }
  __syncthreads();
  // descending exclusive scan: rev index r = 1023-d; thread t owns r in [4t, 4t+4)
  int s = 0;
#pragma unroll
  for (int i = 0; i < 4; ++i) s += cnt[1023 - (t * 4 + i)];
  lds[t] = s;
  __syncthreads();
  for (int o = 1; o < 256; o <<= 1) {
    int v = (t >= o) ? lds[t - o] : 0;
    __syncthreads();
    lds[t] += v;
    __syncthreads();
  }
  int run = lds[t] - s;  // exclusive prefix over rev order
#pragma unroll
  for (int i = 0; i < 4; ++i) {
    int d = 1023 - (t * 4 + i);
    off[d] = run;
    run += cnt[d];
  }
  __syncthreads();
  for (int n = t; n < N_; n += 256) {
    int d = deg[n];
    if (d > 1023) d = 1023;
    int pos = atomicAdd(&off[d], 1);
    perm[pos] = n;
  }
}

// scatter both dirs (blockIdx.y): CSR src ids + eattr permuted to CSR order (fp16)
__global__ void k_scatter(const int* __restrict__ fwd, const int* __restrict__ bwd,
                          const int* __restrict__ rpf, const int* __restrict__ rpb,
                          int* __restrict__ curf, int* __restrict__ curb,
                          int* __restrict__ csf, int* __restrict__ csb,
                          u16* __restrict__ ePf, u16* __restrict__ ePb,
                          const float* __restrict__ eattr) {
  int e = blockIdx.x * 256 + threadIdx.x;
  if (e >= E_) return;
  const int dirb = blockIdx.y;
  const int* src = dirb ? bwd : fwd;
  const int* dst = (dirb ? bwd : fwd) + E_;
  const int* rp = dirb ? rpb : rpf;
  int* cur = dirb ? curb : curf;
  int* csrc = dirb ? csb : csf;
  u16* ePh = dirb ? ePb : ePf;
  int d = dst[e];
  int pos = rp[d] + atomicAdd(&cur[d], 1);
  csrc[pos] = src[e];
  const float4* s4 = reinterpret_cast<const float4*>(eattr + (size_t)e * 16);
  float4 a = s4[0], b = s4[1], c = s4[2], dd = s4[3];
  ushort4 o0, o1, o2, o3;
  o0.x = f2h(a.x); o0.y = f2h(a.y); o0.z = f2h(a.z); o0.w = f2h(a.w);
  o1.x = f2h(b.x); o1.y = f2h(b.y); o1.z = f2h(b.z); o1.w = f2h(b.w);
  o2.x = f2h(c.x); o2.y = f2h(c.y); o2.z = f2h(c.z); o2.w = f2h(c.w);
  o3.x = f2h(dd.x); o3.y = f2h(dd.y); o3.z = f2h(dd.z); o3.w = f2h(dd.w);
  ushort4* d4 = reinterpret_cast<ushort4*>(ePh + (size_t)pos * 16);
  d4[0] = o0; d4[1] = o1; d4[2] = o2; d4[3] = o3;
}

// ============================ fp16 MFMA GEMM (big) ============================
// C[M, Ncols] = A[Mpad, K](fp16) @ Bt[Ncols, K]^T(fp16) + bias(fp32) -> fp16
// 128x128 tile, 4 waves (64x64 quadrant each), global_load_lds staging.
// OPERAND-SWAPPED MFMA: mfma(weights, nodes, acc) so D's lane index = node row and
// the reg-run = 4 consecutive output cols -> ushort4 (8B) epilogue stores.

template <int K>
__global__ __launch_bounds__(256) void k_hgemm(const u16* __restrict__ A,
                                               const u16* __restrict__ Bt,
                                               const float* __restrict__ bias,
                                               u16* __restrict__ Cb, int M, int Ncols) {
  __shared__ __align__(16) u16 As[128 * 128];
  __shared__ __align__(16) u16 Bs[128 * 128];
  const int tid = threadIdx.x;
  const int lane = tid & 63, wave = tid >> 6;
  const int l16 = lane & 15, lq = lane >> 4;
  const int wm = wave & 1, wn = wave >> 1;
  const u16* Arow0 = A + (size_t)blockIdx.y * 128 * K;
  const u16* Brow0 = Bt + (size_t)blockIdx.x * 128 * K;

  f32x4 acc[4][4];  // acc[i=col tile][j=node tile]
#pragma unroll
  for (int i = 0; i < 4; ++i)
#pragma unroll
    for (int j = 0; j < 4; ++j) acc[i][j] = (f32x4){0.f, 0.f, 0.f, 0.f};

  for (int kc = 0; kc < K; kc += 128) {
    if (kc) __syncthreads();
#pragma unroll
    for (int i = 0; i < 8; ++i) {
      int rg = i * 4 + wave;
      int r = rg * 4 + (lane >> 4);
      int cc = kc + (lane & 15) * 8;
      async16(Arow0 + (size_t)r * K + cc, (char*)As + rg * 1024);
      async16(Brow0 + (size_t)r * K + cc, (char*)Bs + rg * 1024);
    }
    __syncthreads();
    const u16* Ab = As + (wm * 64 + l16) * 128 + lq * 8;  // nodes
    const u16* Bb = Bs + (wn * 64 + l16) * 128 + lq * 8;  // weight cols
#pragma unroll
    for (int ks = 0; ks < 4; ++ks) {
      f16x8 af[4], bfr[4];
#pragma unroll
      for (int j = 0; j < 4; ++j)
        af[j] = *reinterpret_cast<const f16x8*>(Ab + j * 16 * 128 + ks * 32);
#pragma unroll
      for (int i = 0; i < 4; ++i)
        bfr[i] = *reinterpret_cast<const f16x8*>(Bb + i * 16 * 128 + ks * 32);
#pragma unroll
      for (int i = 0; i < 4; ++i)
#pragma unroll
        for (int j = 0; j < 4; ++j)
          acc[i][j] = __builtin_amdgcn_mfma_f32_16x16x32_f16(bfr[i], af[j], acc[i][j], 0, 0, 0);
    }
  }

  // Epilogue: lane&15 = node (within j-tile), lq*4+reg = col (within i-tile)
  const int node_base = blockIdx.y * 128 + wm * 64;
  const int col_base = blockIdx.x * 128 + wn * 64;
#pragma unroll
  for (int i = 0; i < 4; ++i) {
    int col0 = col_base + i * 16 + lq * 4;
    float4 bb = *reinterpret_cast<const float4*>(bias + col0);
#pragma unroll
    for (int j = 0; j < 4; ++j) {
      int node = node_base + j * 16 + l16;
      if (node < M) {
        ushort4 o;
        o.x = f2h(acc[i][j][0] + bb.x);
        o.y = f2h(acc[i][j][1] + bb.y);
        o.z = f2h(acc[i][j][2] + bb.z);
        o.w = f2h(acc[i][j][3] + bb.w);
        *reinterpret_cast<ushort4*>(Cb + (size_t)node * Ncols + col0) = o;
      }
    }
  }
}

// ============================ GATv2 aggregation (fused, 4-edge unroll, LPT order) ============================
// Block = one (node, dir) with node = perm[dir][blockIdx.x] (degree-descending -> long
// blocks dispatch first, shrinking the end-of-kernel tail). 128 threads, 4 ch each;
// heads = 32-lane groups. 4 independent gather+eattr chains in flight (latency-bound).
// EE chain in pk-f16; softmax sums fp32 (unnormalized, divide at end).

__global__ __launch_bounds__(128, 4) void k_gat(
    const u16* __restrict__ XLXRh,
    const int* __restrict__ rpf, const int* __restrict__ csf, const u16* __restrict__ ePf,
    const int* __restrict__ rpb, const int* __restrict__ csb, const u16* __restrict__ ePb,
    const int* __restrict__ permf, const int* __restrict__ permb,
    const float* __restrict__ We_f, const float* __restrict__ We_b,
    const float* __restrict__ att_f, const float* __restrict__ att_b,
    const float* __restrict__ bias_f, const float* __restrict__ bias_b,
    u16* __restrict__ FBh, int layer) {
  const int dir = blockIdx.y;
  const int n = (dir ? permb : permf)[blockIdx.x];
  const int* rp = dir ? rpb : rpf;
  const int* cs = dir ? csb : csf;
  const u16* eP = dir ? ePb : ePf;
  const float* We = (dir ? We_b : We_f) + layer * 16 * 512;
  const float* att = (dir ? att_b : att_f) + layer * 512;
  const float* bias = (dir ? bias_b : bias_f) + layer * 128;
  const int t = threadIdx.x;
  const int ch = t << 2;
  const u16* XL = XLXRh + dir * 1024;  // cols [dir*1024, +512) of (N,2048)
  const u16* XR = XL + 512;

  f32x4 a4 = *reinterpret_cast<const f32x4*>(att + ch);
  f16x4 xrh = *reinterpret_cast<const f16x4*>(XR + (size_t)n * 2048 + ch);
  f16x2 xr01 = {xrh.x, xrh.y}, xr23 = {xrh.z, xrh.w};
  f16x2 we01[16], we23[16];  // packed fp16 We rows for this lane's 4 ch
#pragma unroll
  for (int k = 0; k < 16; ++k) {
    float4 w = *reinterpret_cast<const float4*>(We + k * 512 + ch);
    we01[k] = (f16x2){(_Float16)w.x, (_Float16)w.y};
    we23[k] = (f16x2){(_Float16)w.z, (_Float16)w.w};
  }

  // per-lane pre-reduction partial: z = xl+xr+E@We (fp16 pk) -> leaky -> att-dot (f32)
  auto pre = [&](f16x4 x, f16x8 eL, f16x8 eH) -> float {
    f16x2 z01 = (f16x2){x.x, x.y} + xr01;
    f16x2 z23 = (f16x2){x.z, x.w} + xr23;
#pragma unroll
    for (int k = 0; k < 16; ++k) {
      _Float16 sc = (k < 8) ? eL[k] : eH[k - 8];
      f16x2 c = {sc, sc};
      z01 = __builtin_elementwise_fma(c, we01[k], z01);
      z23 = __builtin_elementwise_fma(c, we23[k], z23);
    }
    const f16x2 hz = {(_Float16)0.f, (_Float16)0.f};
    const f16x2 hs = {(_Float16)0.2f, (_Float16)0.2f};
    f16x2 l01 = __builtin_elementwise_fma(hs, __builtin_elementwise_min(z01, hz),
                                          __builtin_elementwise_max(z01, hz));
    f16x2 l23 = __builtin_elementwise_fma(hs, __builtin_elementwise_min(z23, hz),
                                          __builtin_elementwise_max(z23, hz));
    return fmaf((float)l01.x, a4.x,
           fmaf((float)l01.y, a4.y,
           fmaf((float)l23.x, a4.z, (float)l23.y * a4.w)));
  };
  auto accum = [&](float ex, f16x4 x, f32x4& acc) {
    f32x4 xf = {(float)x.x, (float)x.y, (float)x.z, (float)x.w};
    acc = __builtin_elementwise_fma((f32x4){ex, ex, ex, ex}, xf, acc);
  };

  f32x4 acc = {0.f, 0.f, 0.f, 0.f};
  float denom = 0.f;
  const int s = rp[n], epos = rp[n + 1];
  int i = s;
  for (; i + 4 <= epos; i += 4) {
    // 4 independent gather chains in flight
    int s0 = cs[i], s1 = cs[i + 1], s2 = cs[i + 2], s3 = cs[i + 3];
    f16x4 x0 = *reinterpret_cast<const f16x4*>(XL + (size_t)s0 * 2048 + ch);
    f16x4 x1 = *reinterpret_cast<const f16x4*>(XL + (size_t)s1 * 2048 + ch);
    f16x4 x2 = *reinterpret_cast<const f16x4*>(XL + (size_t)s2 * 2048 + ch);
    f16x4 x3 = *reinterpret_cast<const f16x4*>(XL + (size_t)s3 * 2048 + ch);
    f16x8 e0L = *reinterpret_cast<const f16x8*>(eP + (size_t)i * 16);
    f16x8 e0H = *reinterpret_cast<const f16x8*>(eP + (size_t)i * 16 + 8);
    f16x8 e1L = *reinterpret_cast<const f16x8*>(eP + (size_t)(i + 1) * 16);
    f16x8 e1H = *reinterpret_cast<const f16x8*>(eP + (size_t)(i + 1) * 16 + 8);
    f16x8 e2L = *reinterpret_cast<const f16x8*>(eP + (size_t)(i + 2) * 16);
    f16x8 e2H = *reinterpret_cast<const f16x8*>(eP + (size_t)(i + 2) * 16 + 8);
    f16x8 e3L = *reinterpret_cast<const f16x8*>(eP + (size_t)(i + 3) * 16);
    f16x8 e3H = *reinterpret_cast<const f16x8*>(eP + (size_t)(i + 3) * 16 + 8);
    float pA = pre(x0, e0L, e0H);
    float pB = pre(x1, e1L, e1H);
    float pC = pre(x2, e2L, e2H);
    float pD = pre(x3, e3L, e3H);
    // interleaved per-head (32-lane group) reductions
#pragma unroll
    for (int kk = 1; kk < 32; kk <<= 1) {
      pA += __shfl_xor(pA, kk, 32);
      pB += __shfl_xor(pB, kk, 32);
      pC += __shfl_xor(pC, kk, 32);
      pD += __shfl_xor(pD, kk, 32);
    }
    float ex0 = __expf(pA);  // logits O(+-3): no max-subtraction needed
    float ex1 = __expf(pB);
    float ex2 = __expf(pC);
    float ex3 = __expf(pD);
    denom += (ex0 + ex1) + (ex2 + ex3);
    accum(ex0, x0, acc);
    accum(ex1, x1, acc);
    accum(ex2, x2, acc);
    accum(ex3, x3, acc);
  }
  for (; i < epos; ++i) {
    int s0 = cs[i];
    f16x4 x0 = *reinterpret_cast<const f16x4*>(XL + (size_t)s0 * 2048 + ch);
    f16x8 e0L = *reinterpret_cast<const f16x8*>(eP + (size_t)i * 16);
    f16x8 e0H = *reinterpret_cast<const f16x8*>(eP + (size_t)i * 16 + 8);
    float pA = pre(x0, e0L, e0H);
#pragma unroll
    for (int kk = 1; kk < 32; kk <<= 1) pA += __shfl_xor(pA, kk, 32);
    float ex0 = __expf(pA);
    denom += ex0;
    accum(ex0, x0, acc);
  }

  __shared__ __align__(16) float red[512];
  float inv = denom > 0.f ? 1.f / denom : 0.f;  // deg==0 -> out = bias
  *reinterpret_cast<f32x4*>(&red[ch]) = acc * inv;
  __syncthreads();
  if (t < 32) {  // head mean + bias -> fp16
    int c = t << 2;
    f32x4 r0 = *reinterpret_cast<const f32x4*>(&red[c]);
    f32x4 r1 = *reinterpret_cast<const f32x4*>(&red[c + 128]);
    f32x4 r2 = *reinterpret_cast<const f32x4*>(&red[c + 256]);
    f32x4 r3 = *reinterpret_cast<const f32x4*>(&red[c + 384]);
    f32x4 b4 = *reinterpret_cast<const f32x4*>(bias + c);
    f32x4 o = (r0 + r1 + r2 + r3) * 0.25f + b4;
    ushort4 oh;
    oh.x = f2h(o.x); oh.y = f2h(o.y); oh.z = f2h(o.z); oh.w = f2h(o.w);
    *reinterpret_cast<ushort4*>(FBh + (size_t)n * 256 + dir * 128 + c) = oh;
  }
}

// ============================ fused merge MLP + BN stats ============================

__global__ __launch_bounds__(256) void k_mlp(const u16* __restrict__ FBh,
                                             const u16* __restrict__ W1,
                                             const float* __restrict__ b1,
                                             const u16* __restrict__ W2,
                                             const float* __restrict__ b2,
                                             float* __restrict__ M2,
                                             float* __restrict__ STATS) {
  __shared__ __align__(16) u16 As[128 * 128];   // W1 chunk [n][k=128], then W2 [n2][k2]
  __shared__ __align__(16) u16 Bs[64 * 128];    // FB chunk [m][k=128]
  __shared__ __align__(16) u16 M1s[64 * 128];   // M1 [m][k2=128] fp16
  __shared__ float ls[256];
  const int tid = threadIdx.x;
  const int lane = tid & 63, wave = tid >> 6;
  const int l16 = lane & 15, lq = lane >> 4;
  const int mb = blockIdx.x * 64;

  // ---- GEMM1: M1T[128 feat][64 nodes], K=256 ----
  const int wr = wave & 1, wc = wave >> 1;
  f32x4 acc1[4][2];
#pragma unroll
  for (int i = 0; i < 4; ++i)
#pragma unroll
    for (int j = 0; j < 2; ++j) acc1[i][j] = (f32x4){0.f, 0.f, 0.f, 0.f};

  for (int kc = 0; kc < 256; kc += 128) {
    if (kc) __syncthreads();
#pragma unroll
    for (int tI = 0; tI < 8; ++tI) {  // W1: 128 rows x 256B
      int rg = tI * 4 + wave;
      int r = rg * 4 + (lane >> 4);
      async16(W1 + (size_t)r * 256 + kc + (lane & 15) * 8, (char*)As + rg * 1024);
    }
#pragma unroll
    for (int tI = 0; tI < 4; ++tI) {  // FB: 64 rows x 256B
      int rg = tI * 4 + wave;
      int r = rg * 4 + (lane >> 4);
      async16(FBh + (size_t)(mb + r) * 256 + kc + (lane & 15) * 8, (char*)Bs + rg * 1024);
    }
    __syncthreads();
#pragma unroll
    for (int ks = 0; ks < 4; ++ks) {
      f16x8 af[4], bfv[2];
#pragma unroll
      for (int i = 0; i < 4; ++i)
        af[i] = *reinterpret_cast<const f16x8*>(As + (wr * 64 + i * 16 + l16) * 128 + ks * 32 + lq * 8);
#pragma unroll
      for (int j = 0; j < 2; ++j)
        bfv[j] = *reinterpret_cast<const f16x8*>(Bs + (wc * 32 + j * 16 + l16) * 128 + ks * 32 + lq * 8);
#pragma unroll
      for (int i = 0; i < 4; ++i)
#pragma unroll
        for (int j = 0; j < 2; ++j)
          acc1[i][j] = __builtin_amdgcn_mfma_f32_16x16x32_f16(af[i], bfv[j], acc1[i][j], 0, 0, 0);
    }
  }
  ls[tid] = 0.f;  // zero stats partials (used after 2 barriers)
  // epilogue1: bias + relu -> fp16 -> M1s[m][k2] (r-run contiguous in k2)
#pragma unroll
  for (int i = 0; i < 4; ++i) {
    float4 b1v = *reinterpret_cast<const float4*>(b1 + wr * 64 + i * 16 + lq * 4);
    float bb[4] = {b1v.x, b1v.y, b1v.z, b1v.w};
#pragma unroll
    for (int j = 0; j < 2; ++j) {
      int m = wc * 32 + j * 16 + l16;
      int k2 = wr * 64 + i * 16 + lq * 4;
      ushort4 o;
      o.x = f2h(fmaxf(acc1[i][j][0] + bb[0], 0.f));
      o.y = f2h(fmaxf(acc1[i][j][1] + bb[1], 0.f));
      o.z = f2h(fmaxf(acc1[i][j][2] + bb[2], 0.f));
      o.w = f2h(fmaxf(acc1[i][j][3] + bb[3], 0.f));
      *reinterpret_cast<ushort4*>(M1s + m * 128 + k2) = o;
    }
  }
  __syncthreads();  // M1s visible; As free for W2
#pragma unroll
  for (int tI = 0; tI < 8; ++tI) {  // W2: 128 rows x 256B
    int rg = tI * 4 + wave;
    int r = rg * 4 + (lane >> 4);
    async16(W2 + (size_t)r * 128 + (lane & 15) * 8, (char*)As + rg * 1024);
  }
  __syncthreads();

  // ---- GEMM2: M2[64 nodes][128 feat], K=128 ----
  const int wr2 = wave & 1, wc2 = wave >> 1;
  f32x4 acc2[2][4];
#pragma unroll
  for (int i = 0; i < 2; ++i)
#pragma unroll
    for (int j = 0; j < 4; ++j) acc2[i][j] = (f32x4){0.f, 0.f, 0.f, 0.f};
#pragma unroll
  for (int ks = 0; ks < 4; ++ks) {
    f16x8 af2[2], bf2v[4];
#pragma unroll
    for (int i = 0; i < 2; ++i)
      af2[i] = *reinterpret_cast<const f16x8*>(M1s + (wr2 * 32 + i * 16 + l16) * 128 + ks * 32 + lq * 8);
#pragma unroll
    for (int j = 0; j < 4; ++j)
      bf2v[j] = *reinterpret_cast<const f16x8*>(As + (wc2 * 64 + j * 16 + l16) * 128 + ks * 32 + lq * 8);
#pragma unroll
    for (int i = 0; i < 2; ++i)
#pragma unroll
      for (int j = 0; j < 4; ++j)
        acc2[i][j] = __builtin_amdgcn_mfma_f32_16x16x32_f16(af2[i], bf2v[j], acc2[i][j], 0, 0, 0);
  }

  // epilogue2: bias, store M2 (valid rows), BN stats partials
  float s1[4] = {0.f, 0.f, 0.f, 0.f}, s2[4] = {0.f, 0.f, 0.f, 0.f};
  float b2j[4];
#pragma unroll
  for (int j = 0; j < 4; ++j) b2j[j] = b2[wc2 * 64 + j * 16 + l16];
#pragma unroll
  for (int i = 0; i < 2; ++i) {
#pragma unroll
    for (int r = 0; r < 4; ++r) {
      int m = mb + wr2 * 32 + i * 16 + lq * 4 + r;
      if (m < N_) {
#pragma unroll
        for (int j = 0; j < 4; ++j) {
          float v = acc2[i][j][r] + b2j[j];
          M2[(size_t)m * 128 + wc2 * 64 + j * 16 + l16] = v;
          s1[j] += v;
          s2[j] = fmaf(v, v, s2[j]);
        }
      }
    }
  }
#pragma unroll
  for (int j = 0; j < 4; ++j) {
    int c = wc2 * 64 + j * 16 + l16;
    atomicAdd(&ls[c], s1[j]);
    atomicAdd(&ls[128 + c], s2[j]);
  }
  __syncthreads();
  if (tid < 128) {
    atomicAdd(&STATS[tid], ls[tid]);
    atomicAdd(&STATS[128 + tid], ls[128 + tid]);
  }
}

// ============================ BatchNorm finalize ============================

__global__ void k_bn(const float* __restrict__ m2, const float* __restrict__ stats,
                     const float* __restrict__ gamma, const float* __restrict__ beta,
                     u16* __restrict__ houth, float* __restrict__ outf) {
  int idx = blockIdx.x * 256 + threadIdx.x;
  if (idx >= N_ * 32) return;
  int n = idx >> 5;
  int c = (idx & 31) << 2;
  float4 v = *reinterpret_cast<const float4*>(m2 + (size_t)n * 128 + c);
  const float invN = 1.f / (float)N_;
  float o[4];
  float vv[4] = {v.x, v.y, v.z, v.w};
#pragma unroll
  for (int q = 0; q < 4; ++q) {
    float mu = stats[c + q] * invN;
    float var = stats[128 + c + q] * invN - mu * mu;
    float rs = rsqrtf(var + 1e-5f);
    o[q] = fmaxf(gamma[c + q] * (vv[q] - mu) * rs + beta[c + q], 0.f);
  }
  ushort4 oh;
  oh.x = f2h(o[0]); oh.y = f2h(o[1]); oh.z = f2h(o[2]); oh.w = f2h(o[3]);
  *reinterpret_cast<ushort4*>(houth + (size_t)n * 128 + c) = oh;
  if (outf) {
    float4 of = make_float4(o[0], o[1], o[2], o[3]);
    *reinterpret_cast<float4*>(outf + (size_t)n * 128 + c) = of;
  }
}

// ============================ launch ============================

extern "C" void kernel_launch(void* const* d_in, const int* in_sizes, int n_in,
                              void* d_out, int out_size, void* d_ws, size_t ws_size,
                              hipStream_t stream) {
  (void)in_sizes; (void)n_in; (void)out_size; (void)ws_size;
  const float* x      = (const float*)d_in[0];
  const int*   fwd    = (const int*)d_in[1];
  const int*   bwd    = (const int*)d_in[2];
  const float* eattr  = (const float*)d_in[3];
  const float* Wl_f   = (const float*)d_in[4];
  const float* bl_f   = (const float*)d_in[5];
  const float* Wr_f   = (const float*)d_in[6];
  const float* br_f   = (const float*)d_in[7];
  const float* We_f   = (const float*)d_in[8];
  const float* att_f  = (const float*)d_in[9];
  const float* bias_f = (const float*)d_in[10];
  const float* Wl_b   = (const float*)d_in[11];
  const float* bl_b   = (const float*)d_in[12];
  const float* Wr_b   = (const float*)d_in[13];
  const float* br_b   = (const float*)d_in[14];
  const float* We_b   = (const float*)d_in[15];
  const float* att_b  = (const float*)d_in[16];
  const float* bias_b = (const float*)d_in[17];
  const float* Wm1    = (const float*)d_in[18];
  const float* bm1    = (const float*)d_in[19];
  const float* Wm2    = (const float*)d_in[20];
  const float* bm2    = (const float*)d_in[21];
  const float* gamma  = (const float*)d_in[22];
  const float* beta   = (const float*)d_in[23];

  char* ws = (char*)d_ws;
  size_t off = 0;
  auto take = [&](size_t bytes) -> char* {
    char* p = ws + off;
    off += (bytes + 255) & ~(size_t)255;
    return p;
  };
  u16* WCATh = (u16*)take(2ull * 2048 * 128 * 2);
  float* BCAT = (float*)take(2ull * 2048 * 4);
  u16* WM1h = (u16*)take(2ull * 128 * 256 * 2);
  u16* WM2h = (u16*)take(2ull * 128 * 128 * 2);
  u16* Xh    = (u16*)take((size_t)MP_ * 128 * 2);
  u16* HBh   = (u16*)take((size_t)MP_ * 128 * 2);
  u16* XLXRh = (u16*)take((size_t)MP_ * 2048 * 2);
  u16* FBh   = (u16*)take((size_t)MP_ * 256 * 2);
  float* M2  = (float*)take((size_t)MP_ * 128 * 4);
  // DEGS + STATS contiguous: one memset zeroes both
  int* DEGS  = (int*)take(4ull * 40192);
  float* STATS = (float*)take(2ull * 256 * 4);  // per-layer slots
  int* degf = DEGS;
  int* degb = DEGS + (40192 / 4);
  int* curf = DEGS + 2 * (40192 / 4);
  int* curb = DEGS + 3 * (40192 / 4);
  int* rpf = (int*)take((N_ + 1) * 4);
  int* rpb = (int*)take((N_ + 1) * 4);
  int* csf = (int*)take((size_t)E_ * 4);
  int* csb = (int*)take((size_t)E_ * 4);
  int* permf = (int*)take((size_t)N_ * 4);
  int* permb = (int*)take((size_t)N_ * 4);
  u16* ePf = (u16*)take((size_t)E_ * 16 * 2 + 256);
  u16* ePb = (u16*)take((size_t)E_ * 16 * 2 + 256);

  // prep: fused (weights fp16/transposed, x cast, degree hist), scan, dsort, scatter
  hipMemsetAsync(DEGS, 0, 4ull * 40192 + 2ull * 256 * 4, stream);
  k_prep<<<2048, 256, 0, stream>>>(Wl_f, Wr_f, Wl_b, Wr_b, bl_f, br_f, bl_b, br_b,
                                   Wm1, Wm2, WCATh, BCAT, WM1h, WM2h,
                                   x, Xh, fwd + E_, bwd + E_, degf, degb);
  k_scan<<<2, 256, 0, stream>>>(degf, degb, rpf, rpb);
  k_dsort<<<2, 256, 0, stream>>>(degf, degb, permf, permb);
  k_scatter<<<dim3((E_ + 255) / 256, 2), 256, 0, stream>>>(
      fwd, bwd, rpf, rpb, curf, curb, csf, csb, ePf, ePb, eattr);

  for (int l = 0; l < 2; ++l) {
    const u16* hin = (l == 0) ? Xh : HBh;
    // XLXR = hin @ [Wl_f|Wr_f|Wl_b|Wr_b] + biases -> fp16 (N,2048)
    k_hgemm<128><<<dim3(16, MP_ / 128), 256, 0, stream>>>(
        hin, WCATh + (size_t)l * 2048 * 128, BCAT + l * 2048, XLXRh, N_, 2048);
    // GAT aggregation (fused, LPT-ordered), both directions -> FBh (N,256) = [f | b]
    k_gat<<<dim3(N_, 2), 128, 0, stream>>>(XLXRh, rpf, csf, ePf, rpb, csb, ePb,
                                           permf, permb, We_f, We_b, att_f, att_b,
                                           bias_f, bias_b, FBh, l);
    // fused merge MLP + BN stats
    k_mlp<<<MP_ / 64, 256, 0, stream>>>(FBh, WM1h + (size_t)l * 128 * 256, bm1 + l * 128,
                                        WM2h + (size_t)l * 128 * 128, bm2 + l * 128, M2,
                                        STATS + l * 256);
    // BN finalize + ReLU
    k_bn<<<(N_ * 32 + 255) / 256, 256, 0, stream>>>(
        M2, STATS + l * 256, gamma + l * 128, beta + l * 128, HBh,
        (l == 1) ? (float*)d_out : nullptr);
  }
}

// Round 12
// 344.935 us; speedup vs baseline: 1.0910x; 1.0638x over previous
//
#include <hip/hip_runtime.h>

// Problem constants (match reference)
constexpr int N_  = 10000;   // nodes
constexpr int E_  = 100000;  // edges per direction
constexpr int MP_ = 10112;   // N padded to multiple of 128 (79*128)

typedef unsigned int u32;
typedef unsigned short u16;
typedef __attribute__((ext_vector_type(8))) _Float16 f16x8;
typedef __attribute__((ext_vector_type(4))) _Float16 f16x4;
typedef __attribute__((ext_vector_type(2))) _Float16 f16x2;
typedef __attribute__((ext_vector_type(4))) float f32x4;

__device__ __forceinline__ u16 f2h(float f) {  // fp32 -> fp16 bits (RNE)
  _Float16 h = (_Float16)f;
  u16 r;
  __builtin_memcpy(&r, &h, 2);
  return r;
}
__device__ __forceinline__ void async16(const void* g, void* l) {
  // global -> LDS DMA, 16 B/lane; LDS dest = wave-uniform base + lane*16
  __builtin_amdgcn_global_load_lds((const __attribute__((address_space(1))) u32*)g,
                                   (__attribute__((address_space(3))) u32*)l, 16, 0, 0);
}

// ============================ fused prep: weights + x-cast + degree histogram ============================
// WCATh[l][j][k] (fp16, j in [0,2048) = [Wl_f|Wr_f|Wl_b|Wr_b] cols, TRANSPOSED k-contig)
// BCAT [l][2048] fp32; WM1h[l][n][k] k<256; WM2h[l][n][k] k<128 (transposed fp16)
// WePh [dir][l][k][512] fp16 (k_gat preamble reads halved vs fp32)
// Xh = x cast to fp16 (padded); deg histograms for both directions.

__global__ void k_prep(const float* __restrict__ Wl_f, const float* __restrict__ Wr_f,
                       const float* __restrict__ Wl_b, const float* __restrict__ Wr_b,
                       const float* __restrict__ bl_f, const float* __restrict__ br_f,
                       const float* __restrict__ bl_b, const float* __restrict__ br_b,
                       const float* __restrict__ Wm1, const float* __restrict__ Wm2,
                       const float* __restrict__ We_f, const float* __restrict__ We_b,
                       u16* __restrict__ WCATh, float* __restrict__ BCAT,
                       u16* __restrict__ WM1h, u16* __restrict__ WM2h,
                       u16* __restrict__ WePh,
                       const float* __restrict__ x, u16* __restrict__ Xh,
                       const int* __restrict__ fdst, const int* __restrict__ bdst,
                       int* __restrict__ degf, int* __restrict__ degb) {
  int idx = blockIdx.x * 256 + threadIdx.x;
  if (idx < 2 * 2048 * 128) {
    int l = idx >> 18;
    int rem = idx & 262143;
    int j = rem >> 7, k = rem & 127;
    int grp = j >> 9, jj = j & 511;
    const float* W = grp == 0 ? Wl_f : grp == 1 ? Wr_f : grp == 2 ? Wl_b : Wr_b;
    WCATh[idx] = f2h(W[((size_t)(l * 128 + k)) * 512 + jj]);
  }
  if (idx < 2 * 2048) {
    int l = idx >> 11, j = idx & 2047;
    int grp = j >> 9, jj = j & 511;
    const float* bs = grp == 0 ? bl_f : grp == 1 ? br_f : grp == 2 ? bl_b : br_b;
    BCAT[idx] = bs[l * 512 + jj];
  }
  if (idx < 2 * 128 * 256) {  // WM1h[(l*128+n)*256+k] = Wm1[(l*256+k)*128+n]
    int l = idx >> 15;
    int rem = idx & 32767;
    int n = rem >> 8, k = rem & 255;
    WM1h[idx] = f2h(Wm1[((size_t)(l * 256 + k)) * 128 + n]);
  }
  if (idx < 2 * 128 * 128) {  // WM2h[(l*128+n)*128+k] = Wm2[(l*128+k)*128+n]
    int l = idx >> 14;
    int rem = idx & 16383;
    int n = rem >> 7, k = rem & 127;
    WM2h[idx] = f2h(Wm2[((size_t)(l * 128 + k)) * 128 + n]);
  }
  if (idx < 2 * 16384) {  // WePh[dir][l*8192 + k*512 + ch] = fp16(We_{dir})
    int dir = idx >> 14;
    int rem = idx & 16383;
    WePh[idx] = f2h((dir ? We_b : We_f)[rem]);
  }
  if (idx < MP_ * 32) {  // x cast, one thread per 4 elems
    int row = idx >> 5;
    int c4 = (idx & 31) << 2;
    ushort4 o;
    if (row < N_) {
      float4 v = *reinterpret_cast<const float4*>(x + (size_t)row * 128 + c4);
      o.x = f2h(v.x); o.y = f2h(v.y); o.z = f2h(v.z); o.w = f2h(v.w);
    } else {
      o.x = o.y = o.z = o.w = 0;
    }
    *reinterpret_cast<ushort4*>(Xh + (size_t)row * 128 + c4) = o;
  }
  if (idx < E_) {
    atomicAdd(&degf[fdst[idx]], 1);
    atomicAdd(&degb[bdst[idx]], 1);
  }
}

// merged: blocks 0,1 = CSR row-pointer scan (dir 0/1); blocks 2,3 = LPT counting
// sort (degree-descending perm, parallel bin scan). Both read only deg.
__global__ void k_scan(const int* __restrict__ degf, const int* __restrict__ degb,
                       int* __restrict__ rpf, int* __restrict__ rpb,
                       int* __restrict__ permf, int* __restrict__ permb) {
  const int dir = blockIdx.x & 1;
  const int* deg = dir ? degb : degf;
  int t = threadIdx.x;
  __shared__ int lds[256];
  if (blockIdx.x < 2) {
    int* rp = dir ? rpb : rpf;
    const int CH = 40;
    int base = t * CH;
    int s = 0;
    for (int i = 0; i < CH; ++i) {
      int idx = base + i;
      if (idx < N_) s += deg[idx];
    }
    lds[t] = s;
    __syncthreads();
    for (int off = 1; off < 256; off <<= 1) {
      int v = (t >= off) ? lds[t - off] : 0;
      __syncthreads();
      lds[t] += v;
      __syncthreads();
    }
    int run = lds[t] - s;
    for (int i = 0; i < CH; ++i) {
      int idx = base + i;
      if (idx < N_) { rp[idx] = run; run += deg[idx]; }
    }
    if (t == 255) rp[N_] = lds[255];
  } else {
    int* perm = dir ? permb : permf;
    __shared__ int cnt[1024];
    __shared__ int off[1024];
    for (int i = t; i < 1024; i += 256) cnt[i] = 0;
    __syncthreads();
    for (int n = t; n < N_; n += 256) {
      int d = deg[n];
      if (d > 1023) d = 1023;
      atomicAdd(&cnt[d], 1);
    }
    __syncthreads();
    // descending exclusive scan: rev index r = 1023-d; thread t owns [4t, 4t+4)
    int s = 0;
#pragma unroll
    for (int i = 0; i < 4; ++i) s += cnt[1023 - (t * 4 + i)];
    lds[t] = s;
    __syncthreads();
    for (int o = 1; o < 256; o <<= 1) {
      int v = (t >= o) ? lds[t - o] : 0;
      __syncthreads();
      lds[t] += v;
      __syncthreads();
    }
    int run = lds[t] - s;
#pragma unroll
    for (int i = 0; i < 4; ++i) {
      int d = 1023 - (t * 4 + i);
      off[d] = run;
      run += cnt[d];
    }
    __syncthreads();
    for (int n = t; n < N_; n += 256) {
      int d = deg[n];
      if (d > 1023) d = 1023;
      int pos = atomicAdd(&off[d], 1);
      perm[pos] = n;
    }
  }
}

// scatter both dirs (blockIdx.y): CSR src ids + eattr permuted to CSR order (fp16)
__global__ void k_scatter(const int* __restrict__ fwd, const int* __restrict__ bwd,
                          const int* __restrict__ rpf, const int* __restrict__ rpb,
                          int* __restrict__ curf, int* __restrict__ curb,
                          int* __restrict__ csf, int* __restrict__ csb,
                          u16* __restrict__ ePf, u16* __restrict__ ePb,
                          const float* __restrict__ eattr) {
  int e = blockIdx.x * 256 + threadIdx.x;
  if (e >= E_) return;
  const int dirb = blockIdx.y;
  const int* src = dirb ? bwd : fwd;
  const int* dst = (dirb ? bwd : fwd) + E_;
  const int* rp = dirb ? rpb : rpf;
  int* cur = dirb ? curb : curf;
  int* csrc = dirb ? csb : csf;
  u16* ePh = dirb ? ePb : ePf;
  int d = dst[e];
  int pos = rp[d] + atomicAdd(&cur[d], 1);
  csrc[pos] = src[e];
  const float4* s4 = reinterpret_cast<const float4*>(eattr + (size_t)e * 16);
  float4 a = s4[0], b = s4[1], c = s4[2], dd = s4[3];
  ushort4 o0, o1, o2, o3;
  o0.x = f2h(a.x); o0.y = f2h(a.y); o0.z = f2h(a.z); o0.w = f2h(a.w);
  o1.x = f2h(b.x); o1.y = f2h(b.y); o1.z = f2h(b.z); o1.w = f2h(b.w);
  o2.x = f2h(c.x); o2.y = f2h(c.y); o2.z = f2h(c.z); o2.w = f2h(c.w);
  o3.x = f2h(dd.x); o3.y = f2h(dd.y); o3.z = f2h(dd.z); o3.w = f2h(dd.w);
  ushort4* d4 = reinterpret_cast<ushort4*>(ePh + (size_t)pos * 16);
  d4[0] = o0; d4[1] = o1; d4[2] = o2; d4[3] = o3;
}

// ============================ fp16 MFMA GEMM (big) ============================
// C[M, Ncols] = A[Mpad, K](fp16) @ Bt[Ncols, K]^T(fp16) + bias(fp32) -> fp16
// 128x128 tile, 4 waves (64x64 quadrant each), global_load_lds staging.
// OPERAND-SWAPPED MFMA: mfma(weights, nodes, acc) so D's lane index = node row and
// the reg-run = 4 consecutive output cols -> ushort4 (8B) epilogue stores.

template <int K>
__global__ __launch_bounds__(256) void k_hgemm(const u16* __restrict__ A,
                                               const u16* __restrict__ Bt,
                                               const float* __restrict__ bias,
                                               u16* __restrict__ Cb, int M, int Ncols) {
  __shared__ __align__(16) u16 As[128 * 128];
  __shared__ __align__(16) u16 Bs[128 * 128];
  const int tid = threadIdx.x;
  const int lane = tid & 63, wave = tid >> 6;
  const int l16 = lane & 15, lq = lane >> 4;
  const int wm = wave & 1, wn = wave >> 1;
  const u16* Arow0 = A + (size_t)blockIdx.y * 128 * K;
  const u16* Brow0 = Bt + (size_t)blockIdx.x * 128 * K;

  f32x4 acc[4][4];  // acc[i=col tile][j=node tile]
#pragma unroll
  for (int i = 0; i < 4; ++i)
#pragma unroll
    for (int j = 0; j < 4; ++j) acc[i][j] = (f32x4){0.f, 0.f, 0.f, 0.f};

  for (int kc = 0; kc < K; kc += 128) {
    if (kc) __syncthreads();
#pragma unroll
    for (int i = 0; i < 8; ++i) {
      int rg = i * 4 + wave;
      int r = rg * 4 + (lane >> 4);
      int cc = kc + (lane & 15) * 8;
      async16(Arow0 + (size_t)r * K + cc, (char*)As + rg * 1024);
      async16(Brow0 + (size_t)r * K + cc, (char*)Bs + rg * 1024);
    }
    __syncthreads();
    const u16* Ab = As + (wm * 64 + l16) * 128 + lq * 8;  // nodes
    const u16* Bb = Bs + (wn * 64 + l16) * 128 + lq * 8;  // weight cols
#pragma unroll
    for (int ks = 0; ks < 4; ++ks) {
      f16x8 af[4], bfr[4];
#pragma unroll
      for (int j = 0; j < 4; ++j)
        af[j] = *reinterpret_cast<const f16x8*>(Ab + j * 16 * 128 + ks * 32);
#pragma unroll
      for (int i = 0; i < 4; ++i)
        bfr[i] = *reinterpret_cast<const f16x8*>(Bb + i * 16 * 128 + ks * 32);
#pragma unroll
      for (int i = 0; i < 4; ++i)
#pragma unroll
        for (int j = 0; j < 4; ++j)
          acc[i][j] = __builtin_amdgcn_mfma_f32_16x16x32_f16(bfr[i], af[j], acc[i][j], 0, 0, 0);
    }
  }

  // Epilogue: lane&15 = node (within j-tile), lq*4+reg = col (within i-tile)
  const int node_base = blockIdx.y * 128 + wm * 64;
  const int col_base = blockIdx.x * 128 + wn * 64;
#pragma unroll
  for (int i = 0; i < 4; ++i) {
    int col0 = col_base + i * 16 + lq * 4;
    float4 bb = *reinterpret_cast<const float4*>(bias + col0);
#pragma unroll
    for (int j = 0; j < 4; ++j) {
      int node = node_base + j * 16 + l16;
      if (node < M) {
        ushort4 o;
        o.x = f2h(acc[i][j][0] + bb.x);
        o.y = f2h(acc[i][j][1] + bb.y);
        o.z = f2h(acc[i][j][2] + bb.z);
        o.w = f2h(acc[i][j][3] + bb.w);
        *reinterpret_cast<ushort4*>(Cb + (size_t)node * Ncols + col0) = o;
      }
    }
  }
}

// ============================ GATv2 aggregation (fused, 4-edge unroll, LPT order) ============================
// Block = one (node, dir) with node = perm[dir][blockIdx.x] (degree-descending -> long
// blocks dispatch first, shrinking the end-of-kernel tail). 128 threads, 4 ch each;
// heads = 32-lane groups. 4 independent gather+eattr chains in flight (latency-bound).
// We pre-converted to fp16 (WePh): preamble = 16x8B loads, no cvts.
// EE chain in pk-f16; softmax sums fp32 (unnormalized, divide at end).

__global__ __launch_bounds__(128, 4) void k_gat(
    const u16* __restrict__ XLXRh,
    const int* __restrict__ rpf, const int* __restrict__ csf, const u16* __restrict__ ePf,
    const int* __restrict__ rpb, const int* __restrict__ csb, const u16* __restrict__ ePb,
    const int* __restrict__ permf, const int* __restrict__ permb,
    const u16* __restrict__ WePh,
    const float* __restrict__ att_f, const float* __restrict__ att_b,
    const float* __restrict__ bias_f, const float* __restrict__ bias_b,
    u16* __restrict__ FBh, int layer) {
  const int dir = blockIdx.y;
  const int n = (dir ? permb : permf)[blockIdx.x];
  const int* rp = dir ? rpb : rpf;
  const int* cs = dir ? csb : csf;
  const u16* eP = dir ? ePb : ePf;
  const u16* WeP = WePh + dir * 16384 + layer * 8192;
  const float* att = (dir ? att_b : att_f) + layer * 512;
  const float* bias = (dir ? bias_b : bias_f) + layer * 128;
  const int t = threadIdx.x;
  const int ch = t << 2;
  const u16* XL = XLXRh + dir * 1024;  // cols [dir*1024, +512) of (N,2048)
  const u16* XR = XL + 512;

  f32x4 a4 = *reinterpret_cast<const f32x4*>(att + ch);
  f16x4 xrh = *reinterpret_cast<const f16x4*>(XR + (size_t)n * 2048 + ch);
  f16x2 xr01 = {xrh.x, xrh.y}, xr23 = {xrh.z, xrh.w};
  f16x2 we01[16], we23[16];  // packed fp16 We rows for this lane's 4 ch
#pragma unroll
  for (int k = 0; k < 16; ++k) {
    f16x4 w = *reinterpret_cast<const f16x4*>(WeP + k * 512 + ch);
    we01[k] = (f16x2){w.x, w.y};
    we23[k] = (f16x2){w.z, w.w};
  }

  // per-lane pre-reduction partial: z = xl+xr+E@We (fp16 pk) -> leaky -> att-dot (f32)
  auto pre = [&](f16x4 x, f16x8 eL, f16x8 eH) -> float {
    f16x2 z01 = (f16x2){x.x, x.y} + xr01;
    f16x2 z23 = (f16x2){x.z, x.w} + xr23;
#pragma unroll
    for (int k = 0; k < 16; ++k) {
      _Float16 sc = (k < 8) ? eL[k] : eH[k - 8];
      f16x2 c = {sc, sc};
      z01 = __builtin_elementwise_fma(c, we01[k], z01);
      z23 = __builtin_elementwise_fma(c, we23[k], z23);
    }
    const f16x2 hz = {(_Float16)0.f, (_Float16)0.f};
    const f16x2 hs = {(_Float16)0.2f, (_Float16)0.2f};
    f16x2 l01 = __builtin_elementwise_fma(hs, __builtin_elementwise_min(z01, hz),
                                          __builtin_elementwise_max(z01, hz));
    f16x2 l23 = __builtin_elementwise_fma(hs, __builtin_elementwise_min(z23, hz),
                                          __builtin_elementwise_max(z23, hz));
    return fmaf((float)l01.x, a4.x,
           fmaf((float)l01.y, a4.y,
           fmaf((float)l23.x, a4.z, (float)l23.y * a4.w)));
  };
  auto accum = [&](float ex, f16x4 x, f32x4& acc) {
    f32x4 xf = {(float)x.x, (float)x.y, (float)x.z, (float)x.w};
    acc = __builtin_elementwise_fma((f32x4){ex, ex, ex, ex}, xf, acc);
  };

  f32x4 acc = {0.f, 0.f, 0.f, 0.f};
  float denom = 0.f;
  const int s = rp[n], epos = rp[n + 1];
  int i = s;
  for (; i + 4 <= epos; i += 4) {
    // 4 independent gather chains in flight
    int s0 = cs[i], s1 = cs[i + 1], s2 = cs[i + 2], s3 = cs[i + 3];
    f16x4 x0 = *reinterpret_cast<const f16x4*>(XL + (size_t)s0 * 2048 + ch);
    f16x4 x1 = *reinterpret_cast<const f16x4*>(XL + (size_t)s1 * 2048 + ch);
    f16x4 x2 = *reinterpret_cast<const f16x4*>(XL + (size_t)s2 * 2048 + ch);
    f16x4 x3 = *reinterpret_cast<const f16x4*>(XL + (size_t)s3 * 2048 + ch);
    f16x8 e0L = *reinterpret_cast<const f16x8*>(eP + (size_t)i * 16);
    f16x8 e0H = *reinterpret_cast<const f16x8*>(eP + (size_t)i * 16 + 8);
    f16x8 e1L = *reinterpret_cast<const f16x8*>(eP + (size_t)(i + 1) * 16);
    f16x8 e1H = *reinterpret_cast<const f16x8*>(eP + (size_t)(i + 1) * 16 + 8);
    f16x8 e2L = *reinterpret_cast<const f16x8*>(eP + (size_t)(i + 2) * 16);
    f16x8 e2H = *reinterpret_cast<const f16x8*>(eP + (size_t)(i + 2) * 16 + 8);
    f16x8 e3L = *reinterpret_cast<const f16x8*>(eP + (size_t)(i + 3) * 16);
    f16x8 e3H = *reinterpret_cast<const f16x8*>(eP + (size_t)(i + 3) * 16 + 8);
    float pA = pre(x0, e0L, e0H);
    float pB = pre(x1, e1L, e1H);
    float pC = pre(x2, e2L, e2H);
    float pD = pre(x3, e3L, e3H);
    // interleaved per-head (32-lane group) reductions
#pragma unroll
    for (int kk = 1; kk < 32; kk <<= 1) {
      pA += __shfl_xor(pA, kk, 32);
      pB += __shfl_xor(pB, kk, 32);
      pC += __shfl_xor(pC, kk, 32);
      pD += __shfl_xor(pD, kk, 32);
    }
    float ex0 = __expf(pA);  // logits O(+-3): no max-subtraction needed
    float ex1 = __expf(pB);
    float ex2 = __expf(pC);
    float ex3 = __expf(pD);
    denom += (ex0 + ex1) + (ex2 + ex3);
    accum(ex0, x0, acc);
    accum(ex1, x1, acc);
    accum(ex2, x2, acc);
    accum(ex3, x3, acc);
  }
  for (; i < epos; ++i) {
    int s0 = cs[i];
    f16x4 x0 = *reinterpret_cast<const f16x4*>(XL + (size_t)s0 * 2048 + ch);
    f16x8 e0L = *reinterpret_cast<const f16x8*>(eP + (size_t)i * 16);
    f16x8 e0H = *reinterpret_cast<const f16x8*>(eP + (size_t)i * 16 + 8);
    float pA = pre(x0, e0L, e0H);
#pragma unroll
    for (int kk = 1; kk < 32; kk <<= 1) pA += __shfl_xor(pA, kk, 32);
    float ex0 = __expf(pA);
    denom += ex0;
    accum(ex0, x0, acc);
  }

  __shared__ __align__(16) float red[512];
  float inv = denom > 0.f ? 1.f / denom : 0.f;  // deg==0 -> out = bias
  *reinterpret_cast<f32x4*>(&red[ch]) = acc * inv;
  __syncthreads();
  if (t < 32) {  // head mean + bias -> fp16
    int c = t << 2;
    f32x4 r0 = *reinterpret_cast<const f32x4*>(&red[c]);
    f32x4 r1 = *reinterpret_cast<const f32x4*>(&red[c + 128]);
    f32x4 r2 = *reinterpret_cast<const f32x4*>(&red[c + 256]);
    f32x4 r3 = *reinterpret_cast<const f32x4*>(&red[c + 384]);
    f32x4 b4 = *reinterpret_cast<const f32x4*>(bias + c);
    f32x4 o = (r0 + r1 + r2 + r3) * 0.25f + b4;
    ushort4 oh;
    oh.x = f2h(o.x); oh.y = f2h(o.y); oh.z = f2h(o.z); oh.w = f2h(o.w);
    *reinterpret_cast<ushort4*>(FBh + (size_t)n * 256 + dir * 128 + c) = oh;
  }
}

// ============================ fused merge MLP + BN stats ============================

__global__ __launch_bounds__(256) void k_mlp(const u16* __restrict__ FBh,
                                             const u16* __restrict__ W1,
                                             const float* __restrict__ b1,
                                             const u16* __restrict__ W2,
                                             const float* __restrict__ b2,
                                             float* __restrict__ M2,
                                             float* __restrict__ STATS) {
  __shared__ __align__(16) u16 As[128 * 128];   // W1 chunk [n][k=128], then W2 [n2][k2]
  __shared__ __align__(16) u16 Bs[64 * 128];    // FB chunk [m][k=128]
  __shared__ __align__(16) u16 M1s[64 * 128];   // M1 [m][k2=128] fp16
  __shared__ float ls[256];
  const int tid = threadIdx.x;
  const int lane = tid & 63, wave = tid >> 6;
  const int l16 = lane & 15, lq = lane >> 4;
  const int mb = blockIdx.x * 64;

  // ---- GEMM1: M1T[128 feat][64 nodes], K=256 ----
  const int wr = wave & 1, wc = wave >> 1;
  f32x4 acc1[4][2];
#pragma unroll
  for (int i = 0; i < 4; ++i)
#pragma unroll
    for (int j = 0; j < 2; ++j) acc1[i][j] = (f32x4){0.f, 0.f, 0.f, 0.f};

  for (int kc = 0; kc < 256; kc += 128) {
    if (kc) __syncthreads();
#pragma unroll
    for (int tI = 0; tI < 8; ++tI) {  // W1: 128 rows x 256B
      int rg = tI * 4 + wave;
      int r = rg * 4 + (lane >> 4);
      async16(W1 + (size_t)r * 256 + kc + (lane & 15) * 8, (char*)As + rg * 1024);
    }
#pragma unroll
    for (int tI = 0; tI < 4; ++tI) {  // FB: 64 rows x 256B
      int rg = tI * 4 + wave;
      int r = rg * 4 + (lane >> 4);
      async16(FBh + (size_t)(mb + r) * 256 + kc + (lane & 15) * 8, (char*)Bs + rg * 1024);
    }
    __syncthreads();
#pragma unroll
    for (int ks = 0; ks < 4; ++ks) {
      f16x8 af[4], bfv[2];
#pragma unroll
      for (int i = 0; i < 4; ++i)
        af[i] = *reinterpret_cast<const f16x8*>(As + (wr * 64 + i * 16 + l16) * 128 + ks * 32 + lq * 8);
#pragma unroll
      for (int j = 0; j < 2; ++j)
        bfv[j] = *reinterpret_cast<const f16x8*>(Bs + (wc * 32 + j * 16 + l16) * 128 + ks * 32 + lq * 8);
#pragma unroll
      for (int i = 0; i < 4; ++i)
#pragma unroll
        for (int j = 0; j < 2; ++j)
          acc1[i][j] = __builtin_amdgcn_mfma_f32_16x16x32_f16(af[i], bfv[j], acc1[i][j], 0, 0, 0);
    }
  }
  ls[tid] = 0.f;  // zero stats partials (used after 2 barriers)
  // epilogue1: bias + relu -> fp16 -> M1s[m][k2] (r-run contiguous in k2)
#pragma unroll
  for (int i = 0; i < 4; ++i) {
    float4 b1v = *reinterpret_cast<const float4*>(b1 + wr * 64 + i * 16 + lq * 4);
    float bb[4] = {b1v.x, b1v.y, b1v.z, b1v.w};
#pragma unroll
    for (int j = 0; j < 2; ++j) {
      int m = wc * 32 + j * 16 + l16;
      int k2 = wr * 64 + i * 16 + lq * 4;
      ushort4 o;
      o.x = f2h(fmaxf(acc1[i][j][0] + bb[0], 0.f));
      o.y = f2h(fmaxf(acc1[i][j][1] + bb[1], 0.f));
      o.z = f2h(fmaxf(acc1[i][j][2] + bb[2], 0.f));
      o.w = f2h(fmaxf(acc1[i][j][3] + bb[3], 0.f));
      *reinterpret_cast<ushort4*>(M1s + m * 128 + k2) = o;
    }
  }
  __syncthreads();  // M1s visible; As free for W2
#pragma unroll
  for (int tI = 0; tI < 8; ++tI) {  // W2: 128 rows x 256B
    int rg = tI * 4 + wave;
    int r = rg * 4 + (lane >> 4);
    async16(W2 + (size_t)r * 128 + (lane & 15) * 8, (char*)As + rg * 1024);
  }
  __syncthreads();

  // ---- GEMM2: M2[64 nodes][128 feat], K=128 ----
  const int wr2 = wave & 1, wc2 = wave >> 1;
  f32x4 acc2[2][4];
#pragma unroll
  for (int i = 0; i < 2; ++i)
#pragma unroll
    for (int j = 0; j < 4; ++j) acc2[i][j] = (f32x4){0.f, 0.f, 0.f, 0.f};
#pragma unroll
  for (int ks = 0; ks < 4; ++ks) {
    f16x8 af2[2], bf2v[4];
#pragma unroll
    for (int i = 0; i < 2; ++i)
      af2[i] = *reinterpret_cast<const f16x8*>(M1s + (wr2 * 32 + i * 16 + l16) * 128 + ks * 32 + lq * 8);
#pragma unroll
    for (int j = 0; j < 4; ++j)
      bf2v[j] = *reinterpret_cast<const f16x8*>(As + (wc2 * 64 + j * 16 + l16) * 128 + ks * 32 + lq * 8);
#pragma unroll
    for (int i = 0; i < 2; ++i)
#pragma unroll
      for (int j = 0; j < 4; ++j)
        acc2[i][j] = __builtin_amdgcn_mfma_f32_16x16x32_f16(af2[i], bf2v[j], acc2[i][j], 0, 0, 0);
  }

  // epilogue2: bias, store M2 (valid rows), BN stats partials
  float s1[4] = {0.f, 0.f, 0.f, 0.f}, s2[4] = {0.f, 0.f, 0.f, 0.f};
  float b2j[4];
#pragma unroll
  for (int j = 0; j < 4; ++j) b2j[j] = b2[wc2 * 64 + j * 16 + l16];
#pragma unroll
  for (int i = 0; i < 2; ++i) {
#pragma unroll
    for (int r = 0; r < 4; ++r) {
      int m = mb + wr2 * 32 + i * 16 + lq * 4 + r;
      if (m < N_) {
#pragma unroll
        for (int j = 0; j < 4; ++j) {
          float v = acc2[i][j][r] + b2j[j];
          M2[(size_t)m * 128 + wc2 * 64 + j * 16 + l16] = v;
          s1[j] += v;
          s2[j] = fmaf(v, v, s2[j]);
        }
      }
    }
  }
#pragma unroll
  for (int j = 0; j < 4; ++j) {
    int c = wc2 * 64 + j * 16 + l16;
    atomicAdd(&ls[c], s1[j]);
    atomicAdd(&ls[128 + c], s2[j]);
  }
  __syncthreads();
  if (tid < 128) {
    atomicAdd(&STATS[tid], ls[tid]);
    atomicAdd(&STATS[128 + tid], ls[128 + tid]);
  }
}

// ============================ BatchNorm finalize ============================

__global__ void k_bn(const float* __restrict__ m2, const float* __restrict__ stats,
                     const float* __restrict__ gamma, const float* __restrict__ beta,
                     u16* __restrict__ houth, float* __restrict__ outf) {
  int idx = blockIdx.x * 256 + threadIdx.x;
  if (idx >= N_ * 32) return;
  int n = idx >> 5;
  int c = (idx & 31) << 2;
  float4 v = *reinterpret_cast<const float4*>(m2 + (size_t)n * 128 + c);
  const float invN = 1.f / (float)N_;
  float o[4];
  float vv[4] = {v.x, v.y, v.z, v.w};
#pragma unroll
  for (int q = 0; q < 4; ++q) {
    float mu = stats[c + q] * invN;
    float var = stats[128 + c + q] * invN - mu * mu;
    float rs = rsqrtf(var + 1e-5f);
    o[q] = fmaxf(gamma[c + q] * (vv[q] - mu) * rs + beta[c + q], 0.f);
  }
  ushort4 oh;
  oh.x = f2h(o[0]); oh.y = f2h(o[1]); oh.z = f2h(o[2]); oh.w = f2h(o[3]);
  *reinterpret_cast<ushort4*>(houth + (size_t)n * 128 + c) = oh;
  if (outf) {
    float4 of = make_float4(o[0], o[1], o[2], o[3]);
    *reinterpret_cast<float4*>(outf + (size_t)n * 128 + c) = of;
  }
}

// ============================ launch ============================

extern "C" void kernel_launch(void* const* d_in, const int* in_sizes, int n_in,
                              void* d_out, int out_size, void* d_ws, size_t ws_size,
                              hipStream_t stream) {
  (void)in_sizes; (void)n_in; (void)out_size; (void)ws_size;
  const float* x      = (const float*)d_in[0];
  const int*   fwd    = (const int*)d_in[1];
  const int*   bwd    = (const int*)d_in[2];
  const float* eattr  = (const float*)d_in[3];
  const float* Wl_f   = (const float*)d_in[4];
  const float* bl_f   = (const float*)d_in[5];
  const float* Wr_f   = (const float*)d_in[6];
  const float* br_f   = (const float*)d_in[7];
  const float* We_f   = (const float*)d_in[8];
  const float* att_f  = (const float*)d_in[9];
  const float* bias_f = (const float*)d_in[10];
  const float* Wl_b   = (const float*)d_in[11];
  const float* bl_b   = (const float*)d_in[12];
  const float* Wr_b   = (const float*)d_in[13];
  const float* br_b   = (const float*)d_in[14];
  const float* We_b   = (const float*)d_in[15];
  const float* att_b  = (const float*)d_in[16];
  const float* bias_b = (const float*)d_in[17];
  const float* Wm1    = (const float*)d_in[18];
  const float* bm1    = (const float*)d_in[19];
  const float* Wm2    = (const float*)d_in[20];
  const float* bm2    = (const float*)d_in[21];
  const float* gamma  = (const float*)d_in[22];
  const float* beta   = (const float*)d_in[23];

  char* ws = (char*)d_ws;
  size_t off = 0;
  auto take = [&](size_t bytes) -> char* {
    char* p = ws + off;
    off += (bytes + 255) & ~(size_t)255;
    return p;
  };
  u16* WCATh = (u16*)take(2ull * 2048 * 128 * 2);
  float* BCAT = (float*)take(2ull * 2048 * 4);
  u16* WM1h = (u16*)take(2ull * 128 * 256 * 2);
  u16* WM2h = (u16*)take(2ull * 128 * 128 * 2);
  u16* WePh = (u16*)take(2ull * 16384 * 2);
  u16* Xh    = (u16*)take((size_t)MP_ * 128 * 2);
  u16* HBh   = (u16*)take((size_t)MP_ * 128 * 2);
  u16* XLXRh = (u16*)take((size_t)MP_ * 2048 * 2);
  u16* FBh   = (u16*)take((size_t)MP_ * 256 * 2);
  float* M2  = (float*)take((size_t)MP_ * 128 * 4);
  // DEGS + STATS contiguous: one memset zeroes both
  int* DEGS  = (int*)take(4ull * 40192);
  float* STATS = (float*)take(2ull * 256 * 4);  // per-layer slots
  int* degf = DEGS;
  int* degb = DEGS + (40192 / 4);
  int* curf = DEGS + 2 * (40192 / 4);
  int* curb = DEGS + 3 * (40192 / 4);
  int* rpf = (int*)take((N_ + 1) * 4);
  int* rpb = (int*)take((N_ + 1) * 4);
  int* csf = (int*)take((size_t)E_ * 4);
  int* csb = (int*)take((size_t)E_ * 4);
  int* permf = (int*)take((size_t)N_ * 4);
  int* permb = (int*)take((size_t)N_ * 4);
  u16* ePf = (u16*)take((size_t)E_ * 16 * 2 + 256);
  u16* ePb = (u16*)take((size_t)E_ * 16 * 2 + 256);

  // prep: fused (weights fp16/transposed, x cast, degree hist), scan+dsort, scatter
  hipMemsetAsync(DEGS, 0, 4ull * 40192 + 2ull * 256 * 4, stream);
  k_prep<<<2048, 256, 0, stream>>>(Wl_f, Wr_f, Wl_b, Wr_b, bl_f, br_f, bl_b, br_b,
                                   Wm1, Wm2, We_f, We_b, WCATh, BCAT, WM1h, WM2h, WePh,
                                   x, Xh, fwd + E_, bwd + E_, degf, degb);
  k_scan<<<4, 256, 0, stream>>>(degf, degb, rpf, rpb, permf, permb);
  k_scatter<<<dim3((E_ + 255) / 256, 2), 256, 0, stream>>>(
      fwd, bwd, rpf, rpb, curf, curb, csf, csb, ePf, ePb, eattr);

  for (int l = 0; l < 2; ++l) {
    const u16* hin = (l == 0) ? Xh : HBh;
    // XLXR = hin @ [Wl_f|Wr_f|Wl_b|Wr_b] + biases -> fp16 (N,2048)
    k_hgemm<128><<<dim3(16, MP_ / 128), 256, 0, stream>>>(
        hin, WCATh + (size_t)l * 2048 * 128, BCAT + l * 2048, XLXRh, N_, 2048);
    // GAT aggregation (fused, LPT-ordered), both directions -> FBh (N,256) = [f | b]
    k_gat<<<dim3(N_, 2), 128, 0, stream>>>(XLXRh, rpf, csf, ePf, rpb, csb, ePb,
                                           permf, permb, WePh, att_f, att_b,
                                           bias_f, bias_b, FBh, l);
    // fused merge MLP + BN stats
    k_mlp<<<MP_ / 64, 256, 0, stream>>>(FBh, WM1h + (size_t)l * 128 * 256, bm1 + l * 128,
                                        WM2h + (size_t)l * 128 * 128, bm2 + l * 128, M2,
                                        STATS + l * 256);
    // BN finalize + ReLU
    k_bn<<<(N_ * 32 + 255) / 256, 256, 0, stream>>>(
        M2, STATS + l * 256, gamma + l * 128, beta + l * 128, HBh,
        (l == 1) ? (float*)d_out : nullptr);
  }
}